// Round 5
// baseline (474.119 us; speedup 1.0000x reference)
//
#include <hip/hip_runtime.h>
#include <hip/hip_bf16.h>

#define T_LEN   100000   // time samples
#define C_SEL   256      // selected channels
#define C_IN    512      // input channel stride
#define KLOW    12000    // low-pass taps
#define B1      50       // low-pass decimation block
#define NB1     2000     // T_LEN / B1
#define ND1     2001     // low nodes: t = 50*jd, jd = 0..2000
#define NW1     241      // block-averaged low weights
#define ND2E    5003     // out nodes: t = 20*(jo-1), jo = 0..5002 (one extra each side for Catmull-Rom)
#define WH_OFF  5500     // gauss_high truncation start (center 6000 ± 500)
#define KH      1001     // truncated high-pass taps
#define NR2     16       // decimated outputs per node-group (64 VGPR acc; 4.1 loads/node)
#define NQ      (NR2+50) // 66 rows per wave sweep
#define NGX     313      // ceil(5003 / 16) node-groups
#define NPG     5        // phase-groups (4 phases each, one per wave)
#define NWG     (NGX*NPG) // 1565 kC blocks
#define MLEN    5000     // decimated length per phase (T_LEN/20)

typedef __attribute__((ext_vector_type(4))) float f32x4;

// force a wave-uniform float into an SGPR
__device__ __forceinline__ float rf(float x){
  return __int_as_float(__builtin_amdgcn_readfirstlane(__float_as_int(x)));
}

// kA: fused prep + block sums (vectorized).
//  blocks 0..NB1-1: S[jb][c] = 50-sample block sums of selected channels.
//    sel is arange(256) in practice -> contiguous first 1KB of each 2KB row:
//    float4 loads, full-row coalescing; runtime-checked gather fallback.
//  block NB1: W1 (block-averaged low weights), musum=0, cwh = prefix of truncated high kernel.
__global__ __launch_bounds__(256) void kA_prep(const float* __restrict__ x,
                                               const int* __restrict__ sel,
                                               const float* __restrict__ wlow,
                                               const float* __restrict__ whigh,
                                               float* __restrict__ S,
                                               float* __restrict__ W1,
                                               float* __restrict__ musum,
                                               float* __restrict__ cwh){
  if (blockIdx.x < NB1){
    __shared__ f32x4 red[4][64];
    int jb = blockIdx.x;
    int tid = threadIdx.x;
    int c4 = tid & 63;          // float4 column (4 channels)
    int w  = tid >> 6;          // wave id: rows i = w, w+4, ...
    int s0 = sel[4*c4+0], s1 = sel[4*c4+1], s2 = sel[4*c4+2], s3 = sel[4*c4+3];
    bool contig = (s0 == 4*c4) && (s1 == 4*c4+1) && (s2 == 4*c4+2) && (s3 == 4*c4+3);
    bool allc = __all(contig);
    f32x4 acc = {0.f, 0.f, 0.f, 0.f};
    const float* rowb = x + (size_t)jb*(B1*C_IN);
    if (allc){
      for (int i = w; i < B1; i += 4)
        acc += *reinterpret_cast<const f32x4*>(rowb + (size_t)i*C_IN + 4*c4);
    } else {
      for (int i = w; i < B1; i += 4){
        const float* r = rowb + (size_t)i*C_IN;
        f32x4 v = { r[s0], r[s1], r[s2], r[s3] };
        acc += v;
      }
    }
    red[w][c4] = acc;
    __syncthreads();
    if (tid < 64){
      f32x4 s = red[0][tid] + red[1][tid] + red[2][tid] + red[3][tid];
      *reinterpret_cast<f32x4*>(S + (size_t)jb*C_SEL + 4*tid) = s;
    }
  } else {
    int m1 = threadIdx.x;
    if (m1 == 0){
      musum[0] = 0.f;
      float run = 0.f;
      cwh[0] = 0.f;
      for (int j = 0; j < KH; ++j){ run += whigh[WH_OFF + j]; cwh[j+1] = run; }
    }
    if (m1 < NW1){
      float s = 0.f;
      int kbase = 50*m1 - 1;
      for (int off = 0; off < 50; ++off){
        int k = kbase + off;
        if (k >= 0 && k < KLOW) s += wlow[k];
      }
      W1[m1] = s * (1.0f/50.0f);   // block MEAN weight × block SUM of x
    }
  }
}

// kB: decimated low-pass, vectorized: lowd[jd][c] = sum_m1 W1[m1]*S[jd+m1-120][c].
// 4 jd-nodes per block (one per wave); lane = f32x4 column; loop bounds hoisted;
// musum via wave shfl reduce.
__global__ __launch_bounds__(256) void kB_lowd(const float* __restrict__ S,
                                               const float* __restrict__ W1,
                                               float* __restrict__ lowd,
                                               float* __restrict__ musum){
  __shared__ float w1s[NW1];
  int tid = threadIdx.x;
  if (tid < NW1) w1s[tid] = W1[tid];
  __syncthreads();
  int jd   = blockIdx.x*4 + (tid >> 6);
  int lane = tid & 63;
  if (jd >= ND1) return;
  int lo = 120 - jd;  if (lo < 0)   lo = 0;
  int hi = 2119 - jd; if (hi > 240) hi = 240;
  f32x4 acc = {0.f, 0.f, 0.f, 0.f};
  for (int m1 = lo; m1 <= hi; ++m1){
    int jb = jd + m1 - 120;
    acc += w1s[m1] * *reinterpret_cast<const f32x4*>(S + (size_t)jb*C_SEL + 4*lane);
  }
  *reinterpret_cast<f32x4*>(lowd + (size_t)jd*C_SEL + 4*lane) = acc;
  float t = acc.x + acc.y + acc.z + acc.w;
  for (int off = 32; off > 0; off >>= 1) t += __shfl_down(t, off);
  if (lane == 0){
    // sum_t lerp(low)[t] = 25.5*L[0] + 50*L[1..1999] + 24.5*L[2000]
    float ew = (jd == 0) ? 25.5f : ((jd == ND1-1) ? 24.5f : 50.f);
    atomicAdd(musum, ew*t);
  }
}

// kC core: for node jo, conv[jo] = sum_{j=0..1000} whT[j] * xsel[20*(jo-1)+j-499].
// Phase decomposition t = 20m+p: tap j = 20u+p-1, u = m-jo+26 in [0,50];
// whs is the +1-shifted zero-padded kernel so tap(u) = whs[20u+p].
// SGPR-TAP FIX vs previous version: taps are WAVE-UNIFORM -> hoist all 51 into
// SGPRs via readfirstlane (one-time). Hot loop is then: 1 independent global
// f32x4 load + 64 v_fmac with SGPR tap operand per row -- no LDS reads, no tap
// VGPRs, ~50 VGPRs freed for the compiler to pipeline the 66 address-known
// loads many-deep (the R1-R4 kC was latency-serialized on exactly this).
template<bool FAST>
__device__ __forceinline__ void conv_core5(const float* __restrict__ x,
                                           const float* __restrict__ whs,
                                           int m0, int p, int lane,
                                           int s0, int s1, int s2, int s3,
                                           bool allc, f32x4* acc){
  if (FAST){
    float wt_[51];
    #pragma unroll
    for (int u = 0; u < 51; ++u) wt_[u] = rf(whs[20*u + p]);   // SGPR taps
    const float* base = x + (size_t)(20*m0 + p)*C_IN + 4*lane;
    #pragma unroll
    for (int q = 0; q < NQ; ++q){
      f32x4 v = *reinterpret_cast<const f32x4*>(base + (size_t)q*(20*C_IN));
      #pragma unroll
      for (int r = 0; r < NR2; ++r){
        int u = q - r;
        if (u >= 0 && u <= 50) acc[r] += wt_[u]*v;   // static indices after unroll
      }
    }
  } else {
    // edge blocks only (4 of 313 node-groups): guarded loads, LDS taps
    for (int q = 0; q < NQ; ++q){
      int m = m0 + q;
      f32x4 v = {0.f, 0.f, 0.f, 0.f};
      if (m >= 0 && m < MLEN){
        const float* row = x + (size_t)(20*m + p)*C_IN;
        if (allc) v = *reinterpret_cast<const f32x4*>(row + 4*lane);
        else      v = f32x4{ row[s0], row[s1], row[s2], row[s3] };
      }
      #pragma unroll
      for (int r = 0; r < NR2; ++r){
        int u = q - r;
        if (u >= 0 && u <= 50) acc[r] += whs[20*u + p]*v;
      }
    }
  }
}

// kC: per-phase-group partial conv -> outp[pgb][jo][c].
// Grid: 1565 blocks = 313 node-groups x 5 phase-groups (bijective XCD swizzle
// keeps adjacent node-groups on one XCD: 50/66-row window overlap -> L2 hits).
// Block = 4 waves, wave w = phase p = pgb*4+w. Cross-wave reduction chunked
// (4 passes of 4 nodes) so red LDS is 16KB; total LDS 20.5KB.
// No min-waves launch-bound (R1 lesson: never starve the allocator).
__global__ __launch_bounds__(256) void kC_conv(const float* __restrict__ x,
                                               const int* __restrict__ sel,
                                               const float* __restrict__ whigh,
                                               float* __restrict__ outp){
  __shared__ float whs[1024];
  __shared__ f32x4 red[4][4][64];
  int tid = threadIdx.x;
  for (int i = tid; i < 1024; i += 256){
    int j = i - 1;                     // whs[i] = whT[i-1], zero-padded
    whs[i] = (j >= 0 && j < KH) ? whigh[WH_OFF + j] : 0.f;
  }
  // bijective XCD swizzle: NWG=1565, 8 XCDs, q=195, r=5
  int lin = blockIdx.x;
  int xcd = lin & 7, pos = lin >> 3;
  int wg  = (xcd < 5 ? xcd*196 : 980 + (xcd - 5)*195) + pos;
  int xg  = wg % NGX;                  // node-group (fast-varying -> same XCD contiguous)
  int pgb = wg / NGX;                  // phase-group
  int lane = tid & 63;
  int w    = tid >> 6;
  int p    = pgb*4 + w;                // this wave's phase
  int jo0  = xg * NR2;
  int m0   = jo0 - 26;
  int s0 = sel[4*lane+0], s1 = sel[4*lane+1], s2 = sel[4*lane+2], s3 = sel[4*lane+3];
  bool allc = __all((s0 == 4*lane) && (s1 == 4*lane+1) && (s2 == 4*lane+2) && (s3 == 4*lane+3));
  __syncthreads();
  f32x4 acc[NR2];
  #pragma unroll
  for (int r = 0; r < NR2; ++r) acc[r] = f32x4{0.f, 0.f, 0.f, 0.f};
  if (m0 >= 0 && jo0 + NR2 - 1 + 24 < MLEN && allc)
       conv_core5<true >(x, whs, m0, p, lane, s0, s1, s2, s3, allc, acc);
  else conv_core5<false>(x, whs, m0, p, lane, s0, s1, s2, s3, allc, acc);

  // chunked cross-wave reduction: 4 passes x 4 nodes (red = 16KB)
  #pragma unroll
  for (int ch = 0; ch < 4; ++ch){
    if (ch) __syncthreads();
    #pragma unroll
    for (int rr = 0; rr < 4; ++rr) red[w][rr][lane] = acc[ch*4 + rr];
    __syncthreads();
    int r2 = tid >> 6;                 // node within chunk
    int jo = jo0 + ch*4 + r2;
    if (jo < ND2E){
      f32x4 a = red[0][r2][lane] + red[1][r2][lane] + red[2][r2][lane] + red[3][r2][lane];
      *reinterpret_cast<f32x4*>(outp + ((size_t)pgb*ND2E + jo)*C_SEL + 4*lane) = a;
    }
  }
}

// kC2: reduce the 5 phase-group partials and apply the mean/low correction:
// outd[jo] = sum_pg outp[pg][jo] + (mu - low(t_jo)) * s(t_jo)
// s = valid-window mass of the truncated kernel (exact zero-pad edge handling),
// low(t) ~ lerp(lowd) (G_high barely changes low: sigma ratio 20x).
__global__ __launch_bounds__(256) void kC_red(const float* __restrict__ outp,
                                              const float* __restrict__ cwh,
                                              const float* __restrict__ lowd,
                                              const float* __restrict__ musum,
                                              float* __restrict__ outd){
  int tid = threadIdx.x;
  int jo  = blockIdx.x*4 + (tid >> 6);
  int j   = tid & 63;                  // float4 column
  if (jo >= ND2E) return;
  f32x4 a = {0.f, 0.f, 0.f, 0.f};
  #pragma unroll
  for (int pg = 0; pg < NPG; ++pg)
    a += *reinterpret_cast<const f32x4*>(outp + ((size_t)pg*ND2E + jo)*C_SEL + 4*j);
  float mu = musum[0] * (1.0f/((float)T_LEN*(float)C_SEL));
  int tn = 20*(jo - 1);
  int jmin = 499 - tn;             if (jmin < 0) jmin = 0;
  int jmax = T_LEN - 1 + 499 - tn; if (jmax > 1000) jmax = 1000;
  float s = cwh[jmax + 1] - cwh[jmin];
  int tc = tn < 0 ? 0 : (tn > T_LEN-1 ? T_LEN-1 : tn);
  int jd = tc/50, rr = tc - 50*jd;
  float fr = rr*(1.f/50.f);
  f32x4 l0 = *reinterpret_cast<const f32x4*>(lowd + (size_t)jd*C_SEL + 4*j);
  f32x4 l1 = *reinterpret_cast<const f32x4*>(lowd + (size_t)(jd+1)*C_SEL + 4*j);
  f32x4 lo = l0 + (l1 - l0)*fr;
  *reinterpret_cast<f32x4*>(outd + (size_t)jo*C_SEL + 4*j) = a + (mu - lo)*s;
}

// kD: Catmull-Rom interpolation back to full rate, vectorized: lane = f32x4
// column, wave handles full 1KB output rows (store_dwordx4 x 64 lanes/row).
__global__ __launch_bounds__(256) void kD_interp(const float* __restrict__ outd,
                                                 float* __restrict__ out){
  int tid  = threadIdx.x;
  int lane = tid & 63;
  int w    = tid >> 6;
  int t0   = blockIdx.x*8;
  #pragma unroll
  for (int k = 0; k < 2; ++k){
    int t = t0 + w + 4*k;
    int jo = t/20, rr = t - jo*20;
    float a = rr*(1.f/20.f);
    const float* b = outd + (size_t)jo*C_SEL + 4*lane;
    f32x4 p0 = *reinterpret_cast<const f32x4*>(b);
    f32x4 p1 = *reinterpret_cast<const f32x4*>(b +   C_SEL);  // node at t = 20*jo
    f32x4 p2 = *reinterpret_cast<const f32x4*>(b + 2*C_SEL);  // node at t = 20*(jo+1)
    f32x4 p3 = *reinterpret_cast<const f32x4*>(b + 3*C_SEL);
    f32x4 m = p1 + 0.5f*a*((p2 - p0)
            + a*((2.f*p0 - 5.f*p1 + 4.f*p2 - p3)
            + a*(3.f*(p1 - p2) + p3 - p0)));
    *reinterpret_cast<f32x4*>(out + (size_t)t*C_SEL + 4*lane) = m;
  }
}

extern "C" void kernel_launch(void* const* d_in, const int* in_sizes, int n_in,
                              void* d_out, int out_size, void* d_ws, size_t ws_size,
                              hipStream_t stream){
  const float* firings = (const float*)d_in[0];
  const float* glow    = (const float*)d_in[1];
  const float* ghigh   = (const float*)d_in[2];
  const int*   sel     = (const int*)d_in[3];
  float* out = (float*)d_out;
  float* ws  = (float*)d_ws;

  // workspace layout (floats): ~35 MB total
  float* W1    = ws;                 // 256
  float* musum = ws + 256;           // 64 (1 used)
  float* cwh   = ws + 320;           // 1002 (pad to 1728)
  float* S     = ws + 2048;          // 2000*256 = 512000   (ends 514048)
  float* lowd  = ws + 514048;        // 2001*256 = 512256   (ends 1026304)
  float* outd  = ws + 1026304;       // 5003*256 = 1280768  (ends 2307072)
  float* outp  = ws + 2307072;       // 5*5003*256 = 6403840 (ends 8710912)

  hipLaunchKernelGGL(kA_prep,  dim3(NB1+1),    dim3(256), 0, stream,
                     firings, sel, glow, ghigh, S, W1, musum, cwh);
  hipLaunchKernelGGL(kB_lowd,  dim3(501),      dim3(256), 0, stream, S, W1, lowd, musum);
  hipLaunchKernelGGL(kC_conv,  dim3(NWG),      dim3(256), 0, stream,
                     firings, sel, ghigh, outp);
  hipLaunchKernelGGL(kC_red,   dim3(1251),     dim3(256), 0, stream,
                     outp, cwh, lowd, musum, outd);
  hipLaunchKernelGGL(kD_interp,dim3(T_LEN/8),  dim3(256), 0, stream, outd, out);
}

// Round 6
// 470.408 us; speedup vs baseline: 1.0079x; 1.0079x over previous
//
#include <hip/hip_runtime.h>
#include <hip/hip_bf16.h>

#define T_LEN   100000   // time samples
#define C_SEL   256      // selected channels
#define C_IN    512      // input channel stride
#define KLOW    12000    // low-pass taps
#define B1      50       // low-pass decimation block
#define NB1     2000     // T_LEN / B1
#define ND1     2001     // low nodes: t = 50*jd, jd = 0..2000
#define NW1     241      // block-averaged low weights
#define ND2E    5003     // out nodes: t = 20*(jo-1), jo = 0..5002 (one extra each side for Catmull-Rom)
#define WH_OFF  5500     // gauss_high truncation start (center 6000 ± 500)
#define KH      1001     // truncated high-pass taps
#define NR2     16       // decimated outputs per node-group
#define NQ      66       // useful rows per wave sweep (q: u=q-r in [0,50])
#define NCH     17       // staged chunks of 4 rows (68 rows incl. 2 zero-tap)
#define NGX     313      // ceil(5003 / 16) node-groups
#define NPG     5        // phase-groups (4 phases each, one per wave)
#define NWG     (NGX*NPG) // 1565 kC blocks
#define MLEN    5000     // decimated length per phase (T_LEN/20)

typedef __attribute__((ext_vector_type(4))) float f32x4;

// force a wave-uniform float into an SGPR
__device__ __forceinline__ float rf(float x){
  return __int_as_float(__builtin_amdgcn_readfirstlane(__float_as_int(x)));
}

// DMA a 1KB row (64 lanes x 16B) global -> LDS. vmcnt-tracked, no VGPR cost.
// LDS dest is wave-uniform base; HW writes lane L at base + 16*L (linear).
__device__ __forceinline__ void stage16(const float* g, float* l){
  __builtin_amdgcn_global_load_lds((const __attribute__((address_space(1))) void*)g,
                                   (__attribute__((address_space(3))) void*)l,
                                   16, 0, 0);
}

// kA: fused prep + block sums (vectorized).
//  blocks 0..NB1-1: S[jb][c] = 50-sample block sums of selected channels.
//    sel is arange(256) in practice -> contiguous first 1KB of each 2KB row:
//    float4 loads, full-row coalescing; runtime-checked gather fallback.
//  block NB1: W1 (block-averaged low weights), musum=0, cwh = prefix of truncated high kernel.
__global__ __launch_bounds__(256) void kA_prep(const float* __restrict__ x,
                                               const int* __restrict__ sel,
                                               const float* __restrict__ wlow,
                                               const float* __restrict__ whigh,
                                               float* __restrict__ S,
                                               float* __restrict__ W1,
                                               float* __restrict__ musum,
                                               float* __restrict__ cwh){
  if (blockIdx.x < NB1){
    __shared__ f32x4 red[4][64];
    int jb = blockIdx.x;
    int tid = threadIdx.x;
    int c4 = tid & 63;          // float4 column (4 channels)
    int w  = tid >> 6;          // wave id: rows i = w, w+4, ...
    int s0 = sel[4*c4+0], s1 = sel[4*c4+1], s2 = sel[4*c4+2], s3 = sel[4*c4+3];
    bool contig = (s0 == 4*c4) && (s1 == 4*c4+1) && (s2 == 4*c4+2) && (s3 == 4*c4+3);
    bool allc = __all(contig);
    f32x4 acc = {0.f, 0.f, 0.f, 0.f};
    const float* rowb = x + (size_t)jb*(B1*C_IN);
    if (allc){
      for (int i = w; i < B1; i += 4)
        acc += *reinterpret_cast<const f32x4*>(rowb + (size_t)i*C_IN + 4*c4);
    } else {
      for (int i = w; i < B1; i += 4){
        const float* r = rowb + (size_t)i*C_IN;
        f32x4 v = { r[s0], r[s1], r[s2], r[s3] };
        acc += v;
      }
    }
    red[w][c4] = acc;
    __syncthreads();
    if (tid < 64){
      f32x4 s = red[0][tid] + red[1][tid] + red[2][tid] + red[3][tid];
      *reinterpret_cast<f32x4*>(S + (size_t)jb*C_SEL + 4*tid) = s;
    }
  } else {
    int m1 = threadIdx.x;
    if (m1 == 0){
      musum[0] = 0.f;
      float run = 0.f;
      cwh[0] = 0.f;
      for (int j = 0; j < KH; ++j){ run += whigh[WH_OFF + j]; cwh[j+1] = run; }
    }
    if (m1 < NW1){
      float s = 0.f;
      int kbase = 50*m1 - 1;
      for (int off = 0; off < 50; ++off){
        int k = kbase + off;
        if (k >= 0 && k < KLOW) s += wlow[k];
      }
      W1[m1] = s * (1.0f/50.0f);   // block MEAN weight × block SUM of x
    }
  }
}

// kB: decimated low-pass, vectorized: lowd[jd][c] = sum_m1 W1[m1]*S[jd+m1-120][c].
// 4 jd-nodes per block (one per wave); lane = f32x4 column; loop bounds hoisted;
// musum via wave shfl reduce.
__global__ __launch_bounds__(256) void kB_lowd(const float* __restrict__ S,
                                               const float* __restrict__ W1,
                                               float* __restrict__ lowd,
                                               float* __restrict__ musum){
  __shared__ float w1s[NW1];
  int tid = threadIdx.x;
  if (tid < NW1) w1s[tid] = W1[tid];
  __syncthreads();
  int jd   = blockIdx.x*4 + (tid >> 6);
  int lane = tid & 63;
  if (jd >= ND1) return;
  int lo = 120 - jd;  if (lo < 0)   lo = 0;
  int hi = 2119 - jd; if (hi > 240) hi = 240;
  f32x4 acc = {0.f, 0.f, 0.f, 0.f};
  for (int m1 = lo; m1 <= hi; ++m1){
    int jb = jd + m1 - 120;
    acc += w1s[m1] * *reinterpret_cast<const f32x4*>(S + (size_t)jb*C_SEL + 4*lane);
  }
  *reinterpret_cast<f32x4*>(lowd + (size_t)jd*C_SEL + 4*lane) = acc;
  float t = acc.x + acc.y + acc.z + acc.w;
  for (int off = 32; off > 0; off >>= 1) t += __shfl_down(t, off);
  if (lane == 0){
    // sum_t lerp(low)[t] = 25.5*L[0] + 50*L[1..1999] + 24.5*L[2000]
    float ew = (jd == 0) ? 25.5f : ((jd == ND1-1) ? 24.5f : 50.f);
    atomicAdd(musum, ew*t);
  }
}

// kC: for node jo, conv[jo] = sum_{j=0..1000} whT[j] * xsel[20*(jo-1)+j-499].
// Phase decomposition t = 20m+p: tap j = 20u+p-1, u = m-jo+26 in [0,50];
// whs is the +1-shifted zero-padded kernel so tap(u) = whs[20u+p].
//
// DMA-STAGED FAST PATH (the R1-R5 kC was latency-bound at ~10% VALUBusy: loads
// went through VGPRs so pipeline depth = spare registers ~ 2). Now each wave
// stages its phase's rows via global_load_lds (1KB/instr, vmcnt-tracked, zero
// VGPR cost), double-buffered 4-row chunks, counted s_waitcnt vmcnt(4) -- never
// drained to 0 in the steady loop. Waves are phase-private: NO barriers in the
// K-loop. Taps: 19-wide sliding register window (static-indexed, SGPR via
// readfirstlane), 4 uniform LDS reads/chunk -> loop body ~2KB, I$-resident.
__global__ __launch_bounds__(256) void kC_conv(const float* __restrict__ x,
                                               const int* __restrict__ sel,
                                               const float* __restrict__ whigh,
                                               float* __restrict__ outp){
  __shared__ float whs[1024];
  __shared__ float xbuf[4][2][4][256];   // [wave][dbuf][row][ch] = 32 KB
  __shared__ f32x4 red[4][4][64];        // 16 KB
  int tid = threadIdx.x;
  for (int i = tid; i < 1024; i += 256){
    int j = i - 1;                     // whs[i] = whT[i-1], zero-padded
    whs[i] = (j >= 0 && j < KH) ? whigh[WH_OFF + j] : 0.f;
  }
  // bijective XCD swizzle: NWG=1565, 8 XCDs, q=195, r=5
  int lin = blockIdx.x;
  int xcd = lin & 7, pos = lin >> 3;
  int wg  = (xcd < 5 ? xcd*196 : 980 + (xcd - 5)*195) + pos;
  int xg  = wg % NGX;                  // node-group (fast-varying -> same XCD contiguous)
  int pgb = wg / NGX;                  // phase-group
  int lane = tid & 63;
  int wid  = tid >> 6;
  int p    = pgb*4 + wid;              // this wave's phase
  int jo0  = xg * NR2;
  int m0   = jo0 - 26;
  int s0 = sel[4*lane+0], s1 = sel[4*lane+1], s2 = sel[4*lane+2], s3 = sel[4*lane+3];
  bool allc = __all((s0 == 4*lane) && (s1 == 4*lane+1) && (s2 == 4*lane+2) && (s3 == 4*lane+3));
  __syncthreads();
  f32x4 acc[NR2];
  #pragma unroll
  for (int r = 0; r < NR2; ++r) acc[r] = f32x4{0.f, 0.f, 0.f, 0.f};

  if (m0 >= 0 && m0 + 67 < MLEN && allc){
    const size_t rstride = (size_t)20*C_IN;
    const float* gb = x + (size_t)(20*m0 + p)*C_IN + 4*lane;
    // prologue: stage chunks 0,1
    #pragma unroll
    for (int c = 0; c < 2; ++c){
      #pragma unroll
      for (int i2 = 0; i2 < 4; ++i2)
        stage16(gb + (size_t)(4*c + i2)*rstride, &xbuf[wid][c][i2][0]);
    }
    // tap window: wnd[j] = tap(4k+3-j); FMA uses u = 4k+i-r -> j = r-i+3 (static)
    float wnd[19];
    #pragma unroll
    for (int j = 0; j < 19; ++j)
      wnd[j] = (3 - j >= 0) ? rf(whs[20*(3 - j) + p]) : 0.f;
    #pragma unroll 1
    for (int k = 0; k < NCH; ++k){
      if (k < NCH-1) asm volatile("s_waitcnt vmcnt(4)" ::: "memory");  // chunk k resident, k+1 in flight
      else           asm volatile("s_waitcnt vmcnt(0)" ::: "memory");  // last chunk
      f32x4 vv[4];
      #pragma unroll
      for (int i2 = 0; i2 < 4; ++i2)
        vv[i2] = *reinterpret_cast<const f32x4*>(&xbuf[wid][k & 1][i2][4*lane]);
      asm volatile("s_waitcnt lgkmcnt(0)" ::: "memory");   // reads done before restage
      __builtin_amdgcn_sched_barrier(0);
      if (k <= NCH-3){
        #pragma unroll
        for (int i2 = 0; i2 < 4; ++i2)
          stage16(gb + (size_t)(4*(k+2) + i2)*rstride, &xbuf[wid][k & 1][i2][0]);
      }
      __builtin_amdgcn_sched_barrier(0);
      #pragma unroll
      for (int i2 = 0; i2 < 4; ++i2){
        #pragma unroll
        for (int r = 0; r < NR2; ++r)
          acc[r] += wnd[r - i2 + 3] * vv[i2];   // zero taps outside [0,50] add exact 0
      }
      // slide window by 4 for chunk k+1
      #pragma unroll
      for (int j = 18; j >= 4; --j) wnd[j] = wnd[j-4];
      #pragma unroll
      for (int j = 0; j < 4; ++j){
        int u = 4*k + 7 - j;
        wnd[j] = (u <= 50) ? rf(whs[20*u + p]) : 0.f;
      }
    }
  } else {
    // edge node-groups (5 of 313) / non-contig sel: guarded direct loads, LDS taps
    for (int q = 0; q < NQ; ++q){
      int m = m0 + q;
      f32x4 v = {0.f, 0.f, 0.f, 0.f};
      if (m >= 0 && m < MLEN){
        const float* row = x + (size_t)(20*m + p)*C_IN;
        if (allc) v = *reinterpret_cast<const f32x4*>(row + 4*lane);
        else      v = f32x4{ row[s0], row[s1], row[s2], row[s3] };
      }
      #pragma unroll
      for (int r = 0; r < NR2; ++r){
        int u = q - r;
        if (u >= 0 && u <= 50) acc[r] += whs[20*u + p]*v;
      }
    }
  }

  // chunked cross-wave reduction: 4 passes x 4 nodes (red = 16KB)
  #pragma unroll
  for (int ch = 0; ch < 4; ++ch){
    if (ch) __syncthreads();
    #pragma unroll
    for (int rr = 0; rr < 4; ++rr) red[wid][rr][lane] = acc[ch*4 + rr];
    __syncthreads();
    int r2 = tid >> 6;                 // node within chunk
    int jo = jo0 + ch*4 + r2;
    if (jo < ND2E){
      f32x4 a = red[0][r2][lane] + red[1][r2][lane] + red[2][r2][lane] + red[3][r2][lane];
      *reinterpret_cast<f32x4*>(outp + ((size_t)pgb*ND2E + jo)*C_SEL + 4*lane) = a;
    }
  }
}

// kC2: reduce the 5 phase-group partials and apply the mean/low correction:
// outd[jo] = sum_pg outp[pg][jo] + (mu - low(t_jo)) * s(t_jo)
// s = valid-window mass of the truncated kernel (exact zero-pad edge handling),
// low(t) ~ lerp(lowd) (G_high barely changes low: sigma ratio 20x).
__global__ __launch_bounds__(256) void kC_red(const float* __restrict__ outp,
                                              const float* __restrict__ cwh,
                                              const float* __restrict__ lowd,
                                              const float* __restrict__ musum,
                                              float* __restrict__ outd){
  int tid = threadIdx.x;
  int jo  = blockIdx.x*4 + (tid >> 6);
  int j   = tid & 63;                  // float4 column
  if (jo >= ND2E) return;
  f32x4 a = {0.f, 0.f, 0.f, 0.f};
  #pragma unroll
  for (int pg = 0; pg < NPG; ++pg)
    a += *reinterpret_cast<const f32x4*>(outp + ((size_t)pg*ND2E + jo)*C_SEL + 4*j);
  float mu = musum[0] * (1.0f/((float)T_LEN*(float)C_SEL));
  int tn = 20*(jo - 1);
  int jmin = 499 - tn;             if (jmin < 0) jmin = 0;
  int jmax = T_LEN - 1 + 499 - tn; if (jmax > 1000) jmax = 1000;
  float s = cwh[jmax + 1] - cwh[jmin];
  int tc = tn < 0 ? 0 : (tn > T_LEN-1 ? T_LEN-1 : tn);
  int jd = tc/50, rr = tc - 50*jd;
  float fr = rr*(1.f/50.f);
  f32x4 l0 = *reinterpret_cast<const f32x4*>(lowd + (size_t)jd*C_SEL + 4*j);
  f32x4 l1 = *reinterpret_cast<const f32x4*>(lowd + (size_t)(jd+1)*C_SEL + 4*j);
  f32x4 lo = l0 + (l1 - l0)*fr;
  *reinterpret_cast<f32x4*>(outd + (size_t)jo*C_SEL + 4*j) = a + (mu - lo)*s;
}

// kD: Catmull-Rom interpolation back to full rate, vectorized: lane = f32x4
// column, wave handles full 1KB output rows (store_dwordx4 x 64 lanes/row).
__global__ __launch_bounds__(256) void kD_interp(const float* __restrict__ outd,
                                                 float* __restrict__ out){
  int tid  = threadIdx.x;
  int lane = tid & 63;
  int w    = tid >> 6;
  int t0   = blockIdx.x*8;
  #pragma unroll
  for (int k = 0; k < 2; ++k){
    int t = t0 + w + 4*k;
    int jo = t/20, rr = t - jo*20;
    float a = rr*(1.f/20.f);
    const float* b = outd + (size_t)jo*C_SEL + 4*lane;
    f32x4 p0 = *reinterpret_cast<const f32x4*>(b);
    f32x4 p1 = *reinterpret_cast<const f32x4*>(b +   C_SEL);  // node at t = 20*jo
    f32x4 p2 = *reinterpret_cast<const f32x4*>(b + 2*C_SEL);  // node at t = 20*(jo+1)
    f32x4 p3 = *reinterpret_cast<const f32x4*>(b + 3*C_SEL);
    f32x4 m = p1 + 0.5f*a*((p2 - p0)
            + a*((2.f*p0 - 5.f*p1 + 4.f*p2 - p3)
            + a*(3.f*(p1 - p2) + p3 - p0)));
    *reinterpret_cast<f32x4*>(out + (size_t)t*C_SEL + 4*lane) = m;
  }
}

extern "C" void kernel_launch(void* const* d_in, const int* in_sizes, int n_in,
                              void* d_out, int out_size, void* d_ws, size_t ws_size,
                              hipStream_t stream){
  const float* firings = (const float*)d_in[0];
  const float* glow    = (const float*)d_in[1];
  const float* ghigh   = (const float*)d_in[2];
  const int*   sel     = (const int*)d_in[3];
  float* out = (float*)d_out;
  float* ws  = (float*)d_ws;

  // workspace layout (floats): ~35 MB total
  float* W1    = ws;                 // 256
  float* musum = ws + 256;           // 64 (1 used)
  float* cwh   = ws + 320;           // 1002 (pad to 1728)
  float* S     = ws + 2048;          // 2000*256 = 512000   (ends 514048)
  float* lowd  = ws + 514048;        // 2001*256 = 512256   (ends 1026304)
  float* outd  = ws + 1026304;       // 5003*256 = 1280768  (ends 2307072)
  float* outp  = ws + 2307072;       // 5*5003*256 = 6403840 (ends 8710912)

  hipLaunchKernelGGL(kA_prep,  dim3(NB1+1),    dim3(256), 0, stream,
                     firings, sel, glow, ghigh, S, W1, musum, cwh);
  hipLaunchKernelGGL(kB_lowd,  dim3(501),      dim3(256), 0, stream, S, W1, lowd, musum);
  hipLaunchKernelGGL(kC_conv,  dim3(NWG),      dim3(256), 0, stream,
                     firings, sel, ghigh, outp);
  hipLaunchKernelGGL(kC_red,   dim3(1251),     dim3(256), 0, stream,
                     outp, cwh, lowd, musum, outd);
  hipLaunchKernelGGL(kD_interp,dim3(T_LEN/8),  dim3(256), 0, stream, outd, out);
}

// Round 7
// 426.337 us; speedup vs baseline: 1.1121x; 1.1034x over previous
//
#include <hip/hip_runtime.h>
#include <hip/hip_bf16.h>

#define T_LEN   100000   // time samples
#define C_SEL   256      // selected channels
#define C_IN    512      // input channel stride
#define KLOW    12000    // low-pass taps
#define B1      50       // low-pass decimation block
#define NB1     2000     // T_LEN / B1
#define ND1     2001     // low nodes: t = 50*jd, jd = 0..2000
#define NW1     241      // block-averaged low weights
#define ND2E    5003     // out nodes: t = 20*(jo-1), jo = 0..5002
#define WH_OFF  5500     // gauss_high truncation start (center 6000 ± 500)
#define KH      1001     // truncated high-pass taps
#define MLEN    5000     // decimated length per phase
#define TR      50       // input rows per kC block
#define NBLK    2000     // T_LEN / TR
#define NAC     53       // partial nodes per block
#define NSLOT   21       // rotating partial slots (max blocks per node = 21)
#define PROW    ((size_t)ND2E*C_SEL)   // floats per slot plane

typedef __attribute__((ext_vector_type(4))) float f32x4;

// force a wave-uniform float into an SGPR
__device__ __forceinline__ float rf(float x){
  return __int_as_float(__builtin_amdgcn_readfirstlane(__float_as_int(x)));
}

// DMA a 1KB row (64 lanes x 16B) global -> LDS (vmcnt-tracked, no VGPR cost).
__device__ __forceinline__ void stage16(const float* g, float* l){
  __builtin_amdgcn_global_load_lds((const __attribute__((address_space(1))) void*)g,
                                   (__attribute__((address_space(3))) void*)l,
                                   16, 0, 0);
}

// kA: tiny prep. block 0: W1 (block-averaged low weights), musum=0, wht
// (transposed high-tap table wht[p][u] = whT[20u+p-1], zero-padded).
// block 1: cwh = prefix sums of truncated high kernel (chunked parallel scan).
__global__ __launch_bounds__(256) void kA_prep(const float* __restrict__ wlow,
                                               const float* __restrict__ whigh,
                                               float* __restrict__ W1,
                                               float* __restrict__ musum,
                                               float* __restrict__ cwh,
                                               float* __restrict__ wht){
  if (blockIdx.x == 0){
    int m1 = threadIdx.x;
    if (m1 == 0) musum[0] = 0.f;
    if (m1 < NW1){
      float s = 0.f;
      int kbase = 50*m1 - 1;
      for (int off = 0; off < 50; ++off){
        int k = kbase + off;
        if (k >= 0 && k < KLOW) s += wlow[k];
      }
      W1[m1] = s * (1.0f/50.0f);
    }
    for (int k = threadIdx.x; k < 20*51; k += 256){
      int pp = k / 51, u = k - 51*pp;
      int j = 20*u + pp - 1;
      wht[k] = (j >= 0 && j < KH) ? whigh[WH_OFF + j] : 0.f;
    }
  } else {
    __shared__ float part[256];
    __shared__ float pre[257];
    int tg = threadIdx.x;
    float s = 0.f;
    #pragma unroll
    for (int r = 0; r < 4; ++r){ int j = 4*tg + r; if (j < KH) s += whigh[WH_OFF + j]; }
    part[tg] = s;
    __syncthreads();
    if (tg == 0){
      float run = 0.f; pre[0] = 0.f;
      for (int k = 0; k < 256; ++k){ run += part[k]; pre[k+1] = run; }
      cwh[0] = 0.f;
    }
    __syncthreads();
    float base = pre[tg], r0 = 0.f;
    #pragma unroll
    for (int r = 0; r < 4; ++r){
      int j = 4*tg + r;
      if (j < KH){ r0 += whigh[WH_OFF + j]; cwh[j+1] = base + r0; }
    }
  }
}

// kC tile compute: rows t = 50b+i decompose as t = 20m+p, m = mbase + mm,
// p = (i + 10*PAR) % 20, PAR = b&1, mbase = 5*(b/2) + 2*PAR.
// Node jo = m - u + 26 receives tap wht[p][u], u in [0,50].
// acc slot a = jo - (mbase-24) = mm + 50 - u  (all indices static after unroll).
template<int PAR>
__device__ __forceinline__ void tile_conv(const float (*tile)[C_SEL],
                                          const float* __restrict__ wht,
                                          int tid, float* acc, float& ssum){
  // half 1: pp in [0,10): valid mm = PAR==0 ? {0,1,2} : {1,2}
  #pragma unroll 1
  for (int pp = 0; pp < 10; ++pp){
    float tp[51];
    #pragma unroll
    for (int u = 0; u < 51; ++u) tp[u] = rf(wht[pp*51 + u]);
    if (PAR == 0){
      float v0 = tile[pp][tid], v1 = tile[20+pp][tid], v2 = tile[40+pp][tid];
      ssum += v0 + v1 + v2;
      #pragma unroll
      for (int u = 0; u < 51; ++u){
        acc[50-u] += tp[u]*v0; acc[51-u] += tp[u]*v1; acc[52-u] += tp[u]*v2;
      }
    } else {
      float v1 = tile[10+pp][tid], v2 = tile[30+pp][tid];
      ssum += v1 + v2;
      #pragma unroll
      for (int u = 0; u < 51; ++u){
        acc[51-u] += tp[u]*v1; acc[52-u] += tp[u]*v2;
      }
    }
  }
  // half 2: pp in [10,20): valid mm = PAR==0 ? {0,1} : {0,1,2}
  #pragma unroll 1
  for (int pp = 10; pp < 20; ++pp){
    float tp[51];
    #pragma unroll
    for (int u = 0; u < 51; ++u) tp[u] = rf(wht[pp*51 + u]);
    if (PAR == 0){
      float v0 = tile[pp][tid], v1 = tile[20+pp][tid];
      ssum += v0 + v1;
      #pragma unroll
      for (int u = 0; u < 51; ++u){
        acc[50-u] += tp[u]*v0; acc[51-u] += tp[u]*v1;
      }
    } else {
      float v0 = tile[pp-10][tid], v1 = tile[pp+10][tid], v2 = tile[pp+30][tid];
      ssum += v0 + v1 + v2;
      #pragma unroll
      for (int u = 0; u < 51; ++u){
        acc[50-u] += tp[u]*v0; acc[51-u] += tp[u]*v1; acc[52-u] += tp[u]*v2;
      }
    }
  }
}

template<int PAR>
__device__ __forceinline__ void tile_store(const float* acc, int mbase, int b,
                                           int tid, float* __restrict__ pbuf){
  float* pb = pbuf + (size_t)(b % NSLOT)*PROW + tid;
  #pragma unroll
  for (int a = (PAR ? 1 : 0); a < NAC; ++a){   // PAR=1: a=0 slot is exact-zero & never read
    int jo = mbase - 24 + a;
    if (jo >= 0 && jo < ND2E) pb[(size_t)jo*C_SEL] = acc[a];
  }
}

// kC: INPUT-STATIONARY conv. Block b stages rows [50b, 50b+50) once (coalesced,
// read-once globally: 102 MB total vs R3-R6's 425-830 MB reissued), computes
// partials for its 53 touched nodes entirely from LDS, and emits the 50-row
// block sum S[b] for kB as a free by-product. Partials -> rotating slot planes
// (21 consecutive contributing blocks -> distinct slots mod 21; reducer
// enumerates exactly the valid b-range, so no zero-init needed).
__global__ __launch_bounds__(256) void kC_conv(const float* __restrict__ x,
                                               const int* __restrict__ sel,
                                               const float* __restrict__ wht,
                                               float* __restrict__ S,
                                               float* __restrict__ pbuf){
  __shared__ float tile[TR][C_SEL];       // 50 KB -> 3 blocks/CU
  __shared__ int okf;
  int tid = threadIdx.x;
  int b   = blockIdx.x;
  int lane = tid & 63, wid = tid >> 6;
  if (tid == 0) okf = 1;
  __syncthreads();
  if (sel[tid] != tid) okf = 0;           // benign race: all writers store 0
  __syncthreads();
  const float* xrow0 = x + (size_t)b*(TR*C_IN);
  if (okf){
    // wave w stages rows i ≡ w (mod 4): 1KB DMA per row, sequential t-order
    for (int i = wid; i < TR; i += 4)
      stage16(xrow0 + (size_t)i*C_IN + 4*lane, &tile[i][0]);
    asm volatile("s_waitcnt vmcnt(0)" ::: "memory");
    __syncthreads();
  } else {
    int sc = sel[tid];
    for (int i = 0; i < TR; ++i) tile[i][tid] = xrow0[(size_t)i*C_IN + sc];
    __syncthreads();
  }
  float acc[NAC];
  #pragma unroll
  for (int a = 0; a < NAC; ++a) acc[a] = 0.f;
  float ssum = 0.f;
  int mbase = (b >> 1)*5 + (b & 1)*2;
  if (b & 1){ tile_conv<1>(tile, wht, tid, acc, ssum); tile_store<1>(acc, mbase, b, tid, pbuf); }
  else      { tile_conv<0>(tile, wht, tid, acc, ssum); tile_store<0>(acc, mbase, b, tid, pbuf); }
  S[b*C_SEL + tid] = ssum;                // 50-row block sum, free by-product
}

// kB: decimated low-pass (reads S produced by kC): lowd[jd][c] = sum W1[m1]*S[jd+m1-120][c];
// fused trapezoid-weighted musum.
__global__ __launch_bounds__(256) void kB_lowd(const float* __restrict__ S,
                                               const float* __restrict__ W1,
                                               float* __restrict__ lowd,
                                               float* __restrict__ musum){
  __shared__ float w1s[NW1];
  int tid = threadIdx.x;
  if (tid < NW1) w1s[tid] = W1[tid];
  __syncthreads();
  int jd   = blockIdx.x*4 + (tid >> 6);
  int lane = tid & 63;
  if (jd >= ND1) return;
  int lo = 120 - jd;  if (lo < 0)   lo = 0;
  int hi = 2119 - jd; if (hi > 240) hi = 240;
  f32x4 acc = {0.f, 0.f, 0.f, 0.f};
  for (int m1 = lo; m1 <= hi; ++m1){
    int jb = jd + m1 - 120;
    acc += w1s[m1] * *reinterpret_cast<const f32x4*>(S + (size_t)jb*C_SEL + 4*lane);
  }
  *reinterpret_cast<f32x4*>(lowd + (size_t)jd*C_SEL + 4*lane) = acc;
  float t = acc.x + acc.y + acc.z + acc.w;
  for (int off = 32; off > 0; off >>= 1) t += __shfl_down(t, off);
  if (lane == 0){
    float ew = (jd == 0) ? 25.5f : ((jd == ND1-1) ? 24.5f : 50.f);
    atomicAdd(musum, ew*t);
  }
}

// kC_red: sum the <=21 block partials per node (exact valid-b enumeration) and
// apply the mean/low correction: outd[jo] = sum_b pbuf[b%21][jo] + (mu-low)*s.
__global__ __launch_bounds__(256) void kC_red(const float* __restrict__ pbuf,
                                              const float* __restrict__ cwh,
                                              const float* __restrict__ lowd,
                                              const float* __restrict__ musum,
                                              float* __restrict__ outd){
  int tid = threadIdx.x;
  int jo  = blockIdx.x*4 + (tid >> 6);
  int j   = tid & 63;
  if (jo >= ND2E) return;
  int tlo = 20*jo - 519; if (tlo < 0) tlo = 0;
  int thi = 20*jo + 481; if (thi > T_LEN-1) thi = T_LEN-1;
  int blo = tlo/TR, bhi = thi/TR;
  f32x4 a = {0.f, 0.f, 0.f, 0.f};
  for (int b = blo; b <= bhi; ++b)
    a += *reinterpret_cast<const f32x4*>(pbuf + (size_t)(b % NSLOT)*PROW + (size_t)jo*C_SEL + 4*j);
  float mu = musum[0] * (1.0f/((float)T_LEN*(float)C_SEL));
  int tn = 20*(jo - 1);
  int jmin = 499 - tn;             if (jmin < 0) jmin = 0;
  int jmax = T_LEN - 1 + 499 - tn; if (jmax > 1000) jmax = 1000;
  float s = cwh[jmax + 1] - cwh[jmin];
  int tc = tn < 0 ? 0 : (tn > T_LEN-1 ? T_LEN-1 : tn);
  int jd = tc/50, rr = tc - 50*jd;
  float fr = rr*(1.f/50.f);
  f32x4 l0 = *reinterpret_cast<const f32x4*>(lowd + (size_t)jd*C_SEL + 4*j);
  f32x4 l1 = *reinterpret_cast<const f32x4*>(lowd + (size_t)(jd+1)*C_SEL + 4*j);
  f32x4 lo = l0 + (l1 - l0)*fr;
  *reinterpret_cast<f32x4*>(outd + (size_t)jo*C_SEL + 4*j) = a + (mu - lo)*s;
}

// kD: Catmull-Rom interpolation back to full rate (1KB coalesced rows).
__global__ __launch_bounds__(256) void kD_interp(const float* __restrict__ outd,
                                                 float* __restrict__ out){
  int tid  = threadIdx.x;
  int lane = tid & 63;
  int w    = tid >> 6;
  int t0   = blockIdx.x*8;
  #pragma unroll
  for (int k = 0; k < 2; ++k){
    int t = t0 + w + 4*k;
    int jo = t/20, rr = t - jo*20;
    float a = rr*(1.f/20.f);
    const float* bb = outd + (size_t)jo*C_SEL + 4*lane;
    f32x4 p0 = *reinterpret_cast<const f32x4*>(bb);
    f32x4 p1 = *reinterpret_cast<const f32x4*>(bb +   C_SEL);
    f32x4 p2 = *reinterpret_cast<const f32x4*>(bb + 2*C_SEL);
    f32x4 p3 = *reinterpret_cast<const f32x4*>(bb + 3*C_SEL);
    f32x4 m = p1 + 0.5f*a*((p2 - p0)
            + a*((2.f*p0 - 5.f*p1 + 4.f*p2 - p3)
            + a*(3.f*(p1 - p2) + p3 - p0)));
    *reinterpret_cast<f32x4*>(out + (size_t)t*C_SEL + 4*lane) = m;
  }
}

extern "C" void kernel_launch(void* const* d_in, const int* in_sizes, int n_in,
                              void* d_out, int out_size, void* d_ws, size_t ws_size,
                              hipStream_t stream){
  const float* firings = (const float*)d_in[0];
  const float* glow    = (const float*)d_in[1];
  const float* ghigh   = (const float*)d_in[2];
  const int*   sel     = (const int*)d_in[3];
  float* out = (float*)d_out;
  float* ws  = (float*)d_ws;

  // workspace layout (floats): ~117 MB total
  float* W1    = ws;                 // 256
  float* musum = ws + 256;           // 64 (1 used)
  float* cwh   = ws + 320;           // 1002           (ends 1322)
  float* wht   = ws + 1344;          // 1020           (ends 2364)
  float* S     = ws + 2560;          // 2000*256       (ends 514560)
  float* lowd  = ws + 514560;        // 2001*256       (ends 1026816)
  float* outd  = ws + 1026816;       // 5003*256       (ends 2307584)
  float* pbuf  = ws + 2307584;       // 21*5003*256 = 26896128 (ends 29203712)

  hipLaunchKernelGGL(kA_prep,  dim3(2),        dim3(256), 0, stream,
                     glow, ghigh, W1, musum, cwh, wht);
  hipLaunchKernelGGL(kC_conv,  dim3(NBLK),     dim3(256), 0, stream,
                     firings, sel, wht, S, pbuf);
  hipLaunchKernelGGL(kB_lowd,  dim3(501),      dim3(256), 0, stream, S, W1, lowd, musum);
  hipLaunchKernelGGL(kC_red,   dim3(1251),     dim3(256), 0, stream,
                     pbuf, cwh, lowd, musum, outd);
  hipLaunchKernelGGL(kD_interp,dim3(T_LEN/8),  dim3(256), 0, stream, outd, out);
}

// Round 8
// 396.674 us; speedup vs baseline: 1.1952x; 1.0748x over previous
//
#include <hip/hip_runtime.h>
#include <hip/hip_bf16.h>

#define T_LEN   100000   // time samples
#define C_SEL   256      // selected channels
#define C_IN    512      // input channel stride
#define KLOW    12000    // low-pass taps
#define B1      50       // low-pass decimation block
#define NB1     2000     // T_LEN / B1
#define ND1     2001     // low nodes: t = 50*jd, jd = 0..2000
#define NW1     241      // block-averaged low weights
#define ND2E    5003     // out nodes: t = 20*(jo-1), jo = 0..5002
#define WH_OFF  5500     // gauss_high truncation start (center 6000 ± 500)
#define KH      1001     // truncated high-pass taps
#define MLEN    5000     // decimated length per phase
#define TR      50       // input rows per kC block
#define NBLK    2000     // T_LEN / TR
#define NAC     53       // partial nodes per block
#define NSLOT   21       // rotating partial slots (max blocks per node = 21)

typedef __attribute__((ext_vector_type(4))) float f32x4;

// DMA a 1KB row (64 lanes x 16B) global -> LDS (vmcnt-tracked, no VGPR cost).
__device__ __forceinline__ void stage16(const float* g, float* l){
  __builtin_amdgcn_global_load_lds((const __attribute__((address_space(1))) void*)g,
                                   (__attribute__((address_space(3))) void*)l,
                                   16, 0, 0);
}

// kA: tiny prep. block 0: W1 (block-averaged low weights), musum=0, wht
// (transposed high-tap table wht[p][u] = whT[20u+p-1], zero-padded, stride 51).
// block 1: cwh = prefix sums of truncated high kernel (chunked parallel scan).
__global__ __launch_bounds__(256) void kA_prep(const float* __restrict__ wlow,
                                               const float* __restrict__ whigh,
                                               float* __restrict__ W1,
                                               float* __restrict__ musum,
                                               float* __restrict__ cwh,
                                               float* __restrict__ wht){
  if (blockIdx.x == 0){
    int m1 = threadIdx.x;
    if (m1 == 0) musum[0] = 0.f;
    if (m1 < NW1){
      float s = 0.f;
      int kbase = 50*m1 - 1;
      for (int off = 0; off < 50; ++off){
        int k = kbase + off;
        if (k >= 0 && k < KLOW) s += wlow[k];
      }
      W1[m1] = s * (1.0f/50.0f);
    }
    for (int k = threadIdx.x; k < 20*51; k += 256){
      int pp = k / 51, u = k - 51*pp;
      int j = 20*u + pp - 1;
      wht[k] = (j >= 0 && j < KH) ? whigh[WH_OFF + j] : 0.f;
    }
  } else {
    __shared__ float part[256];
    __shared__ float pre[257];
    int tg = threadIdx.x;
    float s = 0.f;
    #pragma unroll
    for (int r = 0; r < 4; ++r){ int j = 4*tg + r; if (j < KH) s += whigh[WH_OFF + j]; }
    part[tg] = s;
    __syncthreads();
    if (tg == 0){
      float run = 0.f; pre[0] = 0.f;
      for (int k = 0; k < 256; ++k){ run += part[k]; pre[k+1] = run; }
      cwh[0] = 0.f;
    }
    __syncthreads();
    float base = pre[tg], r0 = 0.f;
    #pragma unroll
    for (int r = 0; r < 4; ++r){
      int j = 4*tg + r;
      if (j < KH){ r0 += whigh[WH_OFF + j]; cwh[j+1] = base + r0; }
    }
  }
}

// kC tile compute: rows t = 50b+i decompose as t = 20m+p, m = mbase + mm,
// p = (i + 10*PAR) % 20, PAR = b&1, mbase = 5*(b/2) + 2*PAR.
// Node jo = m - u + 26 receives tap whtl[p][u], u in [0,50].
// acc slot a = jo - (mbase-24) = mm + 50 - u  (all indices static after unroll).
// Taps come from LDS via BROADCAST ds_read_b128 (4 taps/read, all lanes same
// addr -> conflict-free) into registers -- R7's per-tap global loads (+rfl)
// were a serialized latency chain on the critical path.
template<int PAR>
__device__ __forceinline__ void tile_conv(const float (*tile)[C_SEL],
                                          const float* __restrict__ whtl,
                                          int tid, float* acc, float& ssum){
  // half 1: pp in [0,10): valid mm = PAR==0 ? {0,1,2} : {1,2}
  #pragma unroll 1
  for (int pp = 0; pp < 10; ++pp){
    f32x4 tpc[13];
    #pragma unroll
    for (int c = 0; c < 13; ++c)
      tpc[c] = *reinterpret_cast<const f32x4*>(&whtl[pp*52 + 4*c]);
    if (PAR == 0){
      float v0 = tile[pp][tid], v1 = tile[20+pp][tid], v2 = tile[40+pp][tid];
      ssum += v0 + v1 + v2;
      #pragma unroll
      for (int u = 0; u < 51; ++u){
        float tp = tpc[u>>2][u&3];
        acc[50-u] += tp*v0; acc[51-u] += tp*v1; acc[52-u] += tp*v2;
      }
    } else {
      float v1 = tile[10+pp][tid], v2 = tile[30+pp][tid];
      ssum += v1 + v2;
      #pragma unroll
      for (int u = 0; u < 51; ++u){
        float tp = tpc[u>>2][u&3];
        acc[51-u] += tp*v1; acc[52-u] += tp*v2;
      }
    }
  }
  // half 2: pp in [10,20): valid mm = PAR==0 ? {0,1} : {0,1,2}
  #pragma unroll 1
  for (int pp = 10; pp < 20; ++pp){
    f32x4 tpc[13];
    #pragma unroll
    for (int c = 0; c < 13; ++c)
      tpc[c] = *reinterpret_cast<const f32x4*>(&whtl[pp*52 + 4*c]);
    if (PAR == 0){
      float v0 = tile[pp][tid], v1 = tile[20+pp][tid];
      ssum += v0 + v1;
      #pragma unroll
      for (int u = 0; u < 51; ++u){
        float tp = tpc[u>>2][u&3];
        acc[50-u] += tp*v0; acc[51-u] += tp*v1;
      }
    } else {
      float v0 = tile[pp-10][tid], v1 = tile[pp+10][tid], v2 = tile[pp+30][tid];
      ssum += v0 + v1 + v2;
      #pragma unroll
      for (int u = 0; u < 51; ++u){
        float tp = tpc[u>>2][u&3];
        acc[50-u] += tp*v0; acc[51-u] += tp*v1; acc[52-u] += tp*v2;
      }
    }
  }
}

// pbuf layout [jo][slot][c]: one node's <=21 partials are 21 CONSECUTIVE KB ->
// kC_red reads stream; kC writes 53 rows at 21KB stride (1KB-granular, fine).
template<int PAR>
__device__ __forceinline__ void tile_store(const float* acc, int mbase, int b,
                                           int tid, float* __restrict__ pbuf){
  float* pb = pbuf + (size_t)(b % NSLOT)*C_SEL + tid;
  #pragma unroll
  for (int a = (PAR ? 1 : 0); a < NAC; ++a){   // PAR=1: a=0 slot is exact-zero & never read
    int jo = mbase - 24 + a;
    if (jo >= 0 && jo < ND2E) pb[(size_t)jo*(NSLOT*C_SEL)] = acc[a];
  }
}

// kC: INPUT-STATIONARY conv. Block b stages rows [50b, 50b+50) once (read-once
// globally: 102 MB), computes partials for its 53 touched nodes from LDS, and
// emits the 50-row block sum S[b] for kB as a free by-product.
__global__ __launch_bounds__(256) void kC_conv(const float* __restrict__ x,
                                               const int* __restrict__ sel,
                                               const float* __restrict__ wht,
                                               float* __restrict__ S,
                                               float* __restrict__ pbuf){
  __shared__ float tile[TR][C_SEL];       // 51.2 KB
  __shared__ float whtl[20*52];           // 4.2 KB (stride 52 = 208B, b128-aligned)
  __shared__ int okf;
  int tid = threadIdx.x;
  int b   = blockIdx.x;
  int lane = tid & 63, wid = tid >> 6;
  if (tid == 0) okf = 1;
  __syncthreads();
  if (sel[tid] != tid) okf = 0;           // benign race: all writers store 0
  for (int k = tid; k < 20*52; k += 256){
    int pp = k / 52, u = k - 52*pp;
    whtl[k] = (u < 51) ? wht[pp*51 + u] : 0.f;
  }
  __syncthreads();
  const float* xrow0 = x + (size_t)b*(TR*C_IN);
  if (okf){
    // wave w stages rows i ≡ w (mod 4): 1KB DMA per row, sequential t-order
    for (int i = wid; i < TR; i += 4)
      stage16(xrow0 + (size_t)i*C_IN + 4*lane, &tile[i][0]);
    asm volatile("s_waitcnt vmcnt(0)" ::: "memory");
    __syncthreads();
  } else {
    int sc = sel[tid];
    for (int i = 0; i < TR; ++i) tile[i][tid] = xrow0[(size_t)i*C_IN + sc];
    __syncthreads();
  }
  float acc[NAC];
  #pragma unroll
  for (int a = 0; a < NAC; ++a) acc[a] = 0.f;
  float ssum = 0.f;
  int mbase = (b >> 1)*5 + (b & 1)*2;
  if (b & 1){ tile_conv<1>(tile, whtl, tid, acc, ssum); tile_store<1>(acc, mbase, b, tid, pbuf); }
  else      { tile_conv<0>(tile, whtl, tid, acc, ssum); tile_store<0>(acc, mbase, b, tid, pbuf); }
  S[b*C_SEL + tid] = ssum;                // 50-row block sum, free by-product
}

// kB: decimated low-pass (reads S produced by kC): lowd[jd][c] = sum W1[m1]*S[jd+m1-120][c];
// fused trapezoid-weighted musum. unroll 4: batch independent loads (S is
// L2-resident; the R7 runtime loop serialized load->wait->fma per iteration).
__global__ __launch_bounds__(256) void kB_lowd(const float* __restrict__ S,
                                               const float* __restrict__ W1,
                                               float* __restrict__ lowd,
                                               float* __restrict__ musum){
  __shared__ float w1s[NW1];
  int tid = threadIdx.x;
  if (tid < NW1) w1s[tid] = W1[tid];
  __syncthreads();
  int jd   = blockIdx.x*4 + (tid >> 6);
  int lane = tid & 63;
  if (jd >= ND1) return;
  int lo = 120 - jd;  if (lo < 0)   lo = 0;
  int hi = 2119 - jd; if (hi > 240) hi = 240;
  f32x4 acc = {0.f, 0.f, 0.f, 0.f};
  #pragma unroll 4
  for (int m1 = lo; m1 <= hi; ++m1){
    int jb = jd + m1 - 120;
    acc += w1s[m1] * *reinterpret_cast<const f32x4*>(S + (size_t)jb*C_SEL + 4*lane);
  }
  *reinterpret_cast<f32x4*>(lowd + (size_t)jd*C_SEL + 4*lane) = acc;
  float t = acc.x + acc.y + acc.z + acc.w;
  for (int off = 32; off > 0; off >>= 1) t += __shfl_down(t, off);
  if (lane == 0){
    float ew = (jd == 0) ? 25.5f : ((jd == ND1-1) ? 24.5f : 50.f);
    atomicAdd(musum, ew*t);
  }
}

// kC_red: sum the valid block partials per node and apply the mean/low
// correction. FULL 21-slot unroll: all loads issue back-to-back over 21
// CONSECUTIVE KB (streaming); invalid slots (edges: garbage/poison) are
// masked with a SELECT (NaN-safe -- multiply-masking poison would poison).
__global__ __launch_bounds__(256) void kC_red(const float* __restrict__ pbuf,
                                              const float* __restrict__ cwh,
                                              const float* __restrict__ lowd,
                                              const float* __restrict__ musum,
                                              float* __restrict__ outd){
  int tid = threadIdx.x;
  int jo  = blockIdx.x*4 + (tid >> 6);
  int j   = tid & 63;
  if (jo >= ND2E) return;
  int tlo = 20*jo - 519; if (tlo < 0) tlo = 0;
  int thi = 20*jo + 481; if (thi > T_LEN-1) thi = T_LEN-1;
  int blo = tlo/TR, bhi = thi/TR;
  int cnt = bhi - blo + 1;
  int sb  = blo % NSLOT;                 // slot of first valid block
  const float* base = pbuf + (size_t)jo*(NSLOT*C_SEL) + 4*j;
  f32x4 a = {0.f, 0.f, 0.f, 0.f};
  #pragma unroll
  for (int k = 0; k < NSLOT; ++k){       // k = slot index (sequential addresses)
    f32x4 v = *reinterpret_cast<const f32x4*>(base + (size_t)k*C_SEL);
    int d = k - sb; if (d < 0) d += NSLOT;
    bool ok = (d < cnt);                 // slot holds a valid b in [blo,bhi]
    a.x += ok ? v.x : 0.f;
    a.y += ok ? v.y : 0.f;
    a.z += ok ? v.z : 0.f;
    a.w += ok ? v.w : 0.f;
  }
  float mu = musum[0] * (1.0f/((float)T_LEN*(float)C_SEL));
  int tn = 20*(jo - 1);
  int jmin = 499 - tn;             if (jmin < 0) jmin = 0;
  int jmax = T_LEN - 1 + 499 - tn; if (jmax > 1000) jmax = 1000;
  float s = cwh[jmax + 1] - cwh[jmin];
  int tc = tn < 0 ? 0 : (tn > T_LEN-1 ? T_LEN-1 : tn);
  int jd = tc/50, rr = tc - 50*jd;
  float fr = rr*(1.f/50.f);
  f32x4 l0 = *reinterpret_cast<const f32x4*>(lowd + (size_t)jd*C_SEL + 4*j);
  f32x4 l1 = *reinterpret_cast<const f32x4*>(lowd + (size_t)(jd+1)*C_SEL + 4*j);
  f32x4 lo = l0 + (l1 - l0)*fr;
  *reinterpret_cast<f32x4*>(outd + (size_t)jo*C_SEL + 4*j) = a + (mu - lo)*s;
}

// kD: Catmull-Rom interpolation back to full rate (1KB coalesced rows).
__global__ __launch_bounds__(256) void kD_interp(const float* __restrict__ outd,
                                                 float* __restrict__ out){
  int tid  = threadIdx.x;
  int lane = tid & 63;
  int w    = tid >> 6;
  int t0   = blockIdx.x*8;
  #pragma unroll
  for (int k = 0; k < 2; ++k){
    int t = t0 + w + 4*k;
    int jo = t/20, rr = t - jo*20;
    float a = rr*(1.f/20.f);
    const float* bb = outd + (size_t)jo*C_SEL + 4*lane;
    f32x4 p0 = *reinterpret_cast<const f32x4*>(bb);
    f32x4 p1 = *reinterpret_cast<const f32x4*>(bb +   C_SEL);
    f32x4 p2 = *reinterpret_cast<const f32x4*>(bb + 2*C_SEL);
    f32x4 p3 = *reinterpret_cast<const f32x4*>(bb + 3*C_SEL);
    f32x4 m = p1 + 0.5f*a*((p2 - p0)
            + a*((2.f*p0 - 5.f*p1 + 4.f*p2 - p3)
            + a*(3.f*(p1 - p2) + p3 - p0)));
    *reinterpret_cast<f32x4*>(out + (size_t)t*C_SEL + 4*lane) = m;
  }
}

extern "C" void kernel_launch(void* const* d_in, const int* in_sizes, int n_in,
                              void* d_out, int out_size, void* d_ws, size_t ws_size,
                              hipStream_t stream){
  const float* firings = (const float*)d_in[0];
  const float* glow    = (const float*)d_in[1];
  const float* ghigh   = (const float*)d_in[2];
  const int*   sel     = (const int*)d_in[3];
  float* out = (float*)d_out;
  float* ws  = (float*)d_ws;

  // workspace layout (floats): ~117 MB total
  float* W1    = ws;                 // 256
  float* musum = ws + 256;           // 64 (1 used)
  float* cwh   = ws + 320;           // 1002           (ends 1322)
  float* wht   = ws + 1344;          // 1020           (ends 2364)
  float* S     = ws + 2560;          // 2000*256       (ends 514560)
  float* lowd  = ws + 514560;        // 2001*256       (ends 1026816)
  float* outd  = ws + 1026816;       // 5003*256       (ends 2307584)
  float* pbuf  = ws + 2307584;       // 5003*21*256 = 26896128 (ends 29203712)

  hipLaunchKernelGGL(kA_prep,  dim3(2),        dim3(256), 0, stream,
                     glow, ghigh, W1, musum, cwh, wht);
  hipLaunchKernelGGL(kC_conv,  dim3(NBLK),     dim3(256), 0, stream,
                     firings, sel, wht, S, pbuf);
  hipLaunchKernelGGL(kB_lowd,  dim3(501),      dim3(256), 0, stream, S, W1, lowd, musum);
  hipLaunchKernelGGL(kC_red,   dim3(1251),     dim3(256), 0, stream,
                     pbuf, cwh, lowd, musum, outd);
  hipLaunchKernelGGL(kD_interp,dim3(T_LEN/8),  dim3(256), 0, stream, outd, out);
}

// Round 9
// 380.719 us; speedup vs baseline: 1.2453x; 1.0419x over previous
//
#include <hip/hip_runtime.h>
#include <hip/hip_bf16.h>

#define T_LEN   100000   // time samples
#define C_SEL   256      // selected channels
#define C_IN    512      // input channel stride
#define KLOW    12000    // low-pass taps
#define B1      50       // low-pass decimation block
#define NB1     2000     // T_LEN / B1
#define ND1     2001     // low nodes: t = 50*jd, jd = 0..2000
#define NW1     241      // block-averaged low weights
#define ND2E    5003     // out nodes: t = 20*(jo-1), jo = 0..5002
#define WH_OFF  5500     // gauss_high truncation start (center 6000 ± 500)
#define KH      1001     // truncated high-pass taps
#define TR      200      // input rows per kC block (4 staged sub-tiles of 50)
#define NBLK    500      // T_LEN / TR
#define NAC     60       // partial nodes per block (jo in [10b-24, 10b+35])
#define NSLOT   6        // rotating partial slots (max 6 blocks per node; (b,b+6) node-disjoint)

typedef __attribute__((ext_vector_type(4))) float f32x4;

// DMA a 1KB row (64 lanes x 16B) global -> LDS (vmcnt-tracked, no VGPR cost).
__device__ __forceinline__ void stage16(const float* g, float* l){
  __builtin_amdgcn_global_load_lds((const __attribute__((address_space(1))) void*)g,
                                   (__attribute__((address_space(3))) void*)l,
                                   16, 0, 0);
}

// kA: tiny prep. block 0: W1 (block-averaged low weights), musum=0, wht
// (transposed high-tap table wht[p][u] = whT[20u+p-1], zero-padded, stride 51).
// block 1: cwh = prefix sums of truncated high kernel (chunked parallel scan).
__global__ __launch_bounds__(256) void kA_prep(const float* __restrict__ wlow,
                                               const float* __restrict__ whigh,
                                               float* __restrict__ W1,
                                               float* __restrict__ musum,
                                               float* __restrict__ cwh,
                                               float* __restrict__ wht){
  if (blockIdx.x == 0){
    int m1 = threadIdx.x;
    if (m1 == 0) musum[0] = 0.f;
    if (m1 < NW1){
      float s = 0.f;
      int kbase = 50*m1 - 1;
      for (int off = 0; off < 50; ++off){
        int k = kbase + off;
        if (k >= 0 && k < KLOW) s += wlow[k];
      }
      W1[m1] = s * (1.0f/50.0f);
    }
    for (int k = threadIdx.x; k < 20*51; k += 256){
      int pp = k / 51, u = k - 51*pp;
      int j = 20*u + pp - 1;
      wht[k] = (j >= 0 && j < KH) ? whigh[WH_OFF + j] : 0.f;
    }
  } else {
    __shared__ float part[256];
    __shared__ float pre[257];
    int tg = threadIdx.x;
    float s = 0.f;
    #pragma unroll
    for (int r = 0; r < 4; ++r){ int j = 4*tg + r; if (j < KH) s += whigh[WH_OFF + j]; }
    part[tg] = s;
    __syncthreads();
    if (tg == 0){
      float run = 0.f; pre[0] = 0.f;
      for (int k = 0; k < 256; ++k){ run += part[k]; pre[k+1] = run; }
      cwh[0] = 0.f;
    }
    __syncthreads();
    float base = pre[tg], r0 = 0.f;
    #pragma unroll
    for (int r = 0; r < 4; ++r){
      int j = 4*tg + r;
      if (j < KH){ r0 += whigh[WH_OFF + j]; cwh[j+1] = base + r0; }
    }
  }
}

// 50-row sub-tile compute: rows t = 50b'+i decompose as t = 20m+p,
// m = mbase(b') + mm, p = (i + 10*PAR) % 20, PAR = b'&1.
// Node jo = m - u + 26 receives tap whtl[p][u], u in [0,50]; acc slot
// (relative to mbase(b')-24) = mm + 50 - u. Caller passes acc+off so the
// 4 sub-tiles of a 200-row block accumulate into one acc[60] register set.
// Taps via broadcast ds_read_b128 (4 taps/read, conflict-free).
template<int PAR>
__device__ __forceinline__ void tile_conv(const float (*tile)[C_SEL],
                                          const float* __restrict__ whtl,
                                          int tid, float* acc, float& ssum){
  // half 1: pp in [0,10): valid mm = PAR==0 ? {0,1,2} : {1,2}
  #pragma unroll 1
  for (int pp = 0; pp < 10; ++pp){
    f32x4 tpc[13];
    #pragma unroll
    for (int c = 0; c < 13; ++c)
      tpc[c] = *reinterpret_cast<const f32x4*>(&whtl[pp*52 + 4*c]);
    if (PAR == 0){
      float v0 = tile[pp][tid], v1 = tile[20+pp][tid], v2 = tile[40+pp][tid];
      ssum += v0 + v1 + v2;
      #pragma unroll
      for (int u = 0; u < 51; ++u){
        float tp = tpc[u>>2][u&3];
        acc[50-u] += tp*v0; acc[51-u] += tp*v1; acc[52-u] += tp*v2;
      }
    } else {
      float v1 = tile[10+pp][tid], v2 = tile[30+pp][tid];
      ssum += v1 + v2;
      #pragma unroll
      for (int u = 0; u < 51; ++u){
        float tp = tpc[u>>2][u&3];
        acc[51-u] += tp*v1; acc[52-u] += tp*v2;
      }
    }
  }
  // half 2: pp in [10,20): valid mm = PAR==0 ? {0,1} : {0,1,2}
  #pragma unroll 1
  for (int pp = 10; pp < 20; ++pp){
    f32x4 tpc[13];
    #pragma unroll
    for (int c = 0; c < 13; ++c)
      tpc[c] = *reinterpret_cast<const f32x4*>(&whtl[pp*52 + 4*c]);
    if (PAR == 0){
      float v0 = tile[pp][tid], v1 = tile[20+pp][tid];
      ssum += v0 + v1;
      #pragma unroll
      for (int u = 0; u < 51; ++u){
        float tp = tpc[u>>2][u&3];
        acc[50-u] += tp*v0; acc[51-u] += tp*v1;
      }
    } else {
      float v0 = tile[pp-10][tid], v1 = tile[pp+10][tid], v2 = tile[pp+30][tid];
      ssum += v0 + v1 + v2;
      #pragma unroll
      for (int u = 0; u < 51; ++u){
        float tp = tpc[u>>2][u&3];
        acc[50-u] += tp*v0; acc[51-u] += tp*v1; acc[52-u] += tp*v2;
      }
    }
  }
}

// kC: INPUT-STATIONARY conv, TR=200. Block b stages 4 sequential 50-row
// sub-tiles (same 50KB LDS buffer; 2 blocks/CU so staging overlaps the other
// block's compute), accumulating acc[60] in registers; ONE pbuf store at the
// end -> partial traffic 215 MB (R8) -> 60 MB. Sub-tile q == old block
// b' = 4b+q: PAR = q&1, acc offset = 5*(q>>1) + 2*(q&1) = {0,2,5,7}.
// Emits the four 50-row block sums S[4b+q] for kB as a free by-product.
__global__ __launch_bounds__(256) void kC_conv(const float* __restrict__ x,
                                               const int* __restrict__ sel,
                                               const float* __restrict__ wht,
                                               float* __restrict__ S,
                                               float* __restrict__ pbuf){
  __shared__ float tile[50][C_SEL];       // 50 KB (reused by the 4 sub-tiles)
  __shared__ float whtl[20*52];           // 4.2 KB (stride 52 = 208B, b128-aligned)
  __shared__ int okf;
  int tid = threadIdx.x;
  int b   = blockIdx.x;
  int lane = tid & 63, wid = tid >> 6;
  if (tid == 0) okf = 1;
  __syncthreads();
  if (sel[tid] != tid) okf = 0;           // benign race: all writers store 0
  for (int k = tid; k < 20*52; k += 256){
    int pp = k / 52, u = k - 52*pp;
    whtl[k] = (u < 51) ? wht[pp*51 + u] : 0.f;
  }
  __syncthreads();
  float acc[NAC];
  #pragma unroll
  for (int a = 0; a < NAC; ++a) acc[a] = 0.f;
  int ok = okf;
  int sc = sel[tid];
  #pragma unroll
  for (int q = 0; q < 4; ++q){
    const float* xrow0 = x + (size_t)(4*b + q)*(50*C_IN);
    if (ok){
      for (int i = wid; i < 50; i += 4)
        stage16(xrow0 + (size_t)i*C_IN + 4*lane, &tile[i][0]);
      asm volatile("s_waitcnt vmcnt(0)" ::: "memory");
      __syncthreads();                    // DMA visible to all waves
    } else {
      for (int i = 0; i < 50; ++i) tile[i][tid] = xrow0[(size_t)i*C_IN + sc];
      __syncthreads();
    }
    float ssum = 0.f;
    const int off = 5*(q>>1) + 2*(q&1);   // compile-time after unroll
    if (q & 1) tile_conv<1>(tile, whtl, tid, acc + off, ssum);
    else       tile_conv<0>(tile, whtl, tid, acc + off, ssum);
    S[(4*b + q)*C_SEL + tid] = ssum;      // 50-row block sum, free by-product
    __syncthreads();                      // all reads done before restage
  }
  // one store pass: pbuf[jo][b%6][c]; (b, b+6) write disjoint jo-ranges.
  float* pb = pbuf + (size_t)(b % NSLOT)*C_SEL + tid;
  int jo0 = 10*b - 24;
  #pragma unroll
  for (int a = 0; a < NAC; ++a){
    int jo = jo0 + a;
    if (jo >= 0 && jo < ND2E) pb[(size_t)jo*(NSLOT*C_SEL)] = acc[a];
  }
}

// kB: decimated low-pass (reads S produced by kC): lowd[jd][c] = sum W1[m1]*S[jd+m1-120][c];
// fused trapezoid-weighted musum. unroll 4 batches independent L2 loads.
__global__ __launch_bounds__(256) void kB_lowd(const float* __restrict__ S,
                                               const float* __restrict__ W1,
                                               float* __restrict__ lowd,
                                               float* __restrict__ musum){
  __shared__ float w1s[NW1];
  int tid = threadIdx.x;
  if (tid < NW1) w1s[tid] = W1[tid];
  __syncthreads();
  int jd   = blockIdx.x*4 + (tid >> 6);
  int lane = tid & 63;
  if (jd >= ND1) return;
  int lo = 120 - jd;  if (lo < 0)   lo = 0;
  int hi = 2119 - jd; if (hi > 240) hi = 240;
  f32x4 acc = {0.f, 0.f, 0.f, 0.f};
  #pragma unroll 4
  for (int m1 = lo; m1 <= hi; ++m1){
    int jb = jd + m1 - 120;
    acc += w1s[m1] * *reinterpret_cast<const f32x4*>(S + (size_t)jb*C_SEL + 4*lane);
  }
  *reinterpret_cast<f32x4*>(lowd + (size_t)jd*C_SEL + 4*lane) = acc;
  float t = acc.x + acc.y + acc.z + acc.w;
  for (int off = 32; off > 0; off >>= 1) t += __shfl_down(t, off);
  if (lane == 0){
    float ew = (jd == 0) ? 25.5f : ((jd == ND1-1) ? 24.5f : 50.f);
    atomicAdd(musum, ew*t);
  }
}

// kC_red: sum the valid block partials per node (full 6-slot unroll, loads
// issue back-to-back over 6 consecutive KB) and apply the mean/low correction.
// Invalid slots (edges: garbage/poison) masked with SELECT (NaN-safe).
__global__ __launch_bounds__(256) void kC_red(const float* __restrict__ pbuf,
                                              const float* __restrict__ cwh,
                                              const float* __restrict__ lowd,
                                              const float* __restrict__ musum,
                                              float* __restrict__ outd){
  int tid = threadIdx.x;
  int jo  = blockIdx.x*4 + (tid >> 6);
  int j   = tid & 63;
  if (jo >= ND2E) return;
  int tlo = 20*jo - 519; if (tlo < 0) tlo = 0;
  int thi = 20*jo + 481; if (thi > T_LEN-1) thi = T_LEN-1;
  int blo = tlo/TR, bhi = thi/TR;
  int cnt = bhi - blo + 1;
  int sb  = blo % NSLOT;                 // slot of first valid block
  const float* base = pbuf + (size_t)jo*(NSLOT*C_SEL) + 4*j;
  f32x4 a = {0.f, 0.f, 0.f, 0.f};
  #pragma unroll
  for (int k = 0; k < NSLOT; ++k){       // k = slot index (sequential addresses)
    f32x4 v = *reinterpret_cast<const f32x4*>(base + (size_t)k*C_SEL);
    int d = k - sb; if (d < 0) d += NSLOT;
    bool ok = (d < cnt);                 // slot holds a valid b in [blo,bhi]
    a.x += ok ? v.x : 0.f;
    a.y += ok ? v.y : 0.f;
    a.z += ok ? v.z : 0.f;
    a.w += ok ? v.w : 0.f;
  }
  float mu = musum[0] * (1.0f/((float)T_LEN*(float)C_SEL));
  int tn = 20*(jo - 1);
  int jmin = 499 - tn;             if (jmin < 0) jmin = 0;
  int jmax = T_LEN - 1 + 499 - tn; if (jmax > 1000) jmax = 1000;
  float s = cwh[jmax + 1] - cwh[jmin];
  int tc = tn < 0 ? 0 : (tn > T_LEN-1 ? T_LEN-1 : tn);
  int jd = tc/50, rr = tc - 50*jd;
  float fr = rr*(1.f/50.f);
  f32x4 l0 = *reinterpret_cast<const f32x4*>(lowd + (size_t)jd*C_SEL + 4*j);
  f32x4 l1 = *reinterpret_cast<const f32x4*>(lowd + (size_t)(jd+1)*C_SEL + 4*j);
  f32x4 lo = l0 + (l1 - l0)*fr;
  *reinterpret_cast<f32x4*>(outd + (size_t)jo*C_SEL + 4*j) = a + (mu - lo)*s;
}

// kD: Catmull-Rom interpolation back to full rate (1KB coalesced rows).
__global__ __launch_bounds__(256) void kD_interp(const float* __restrict__ outd,
                                                 float* __restrict__ out){
  int tid  = threadIdx.x;
  int lane = tid & 63;
  int w    = tid >> 6;
  int t0   = blockIdx.x*8;
  #pragma unroll
  for (int k = 0; k < 2; ++k){
    int t = t0 + w + 4*k;
    int jo = t/20, rr = t - jo*20;
    float a = rr*(1.f/20.f);
    const float* bb = outd + (size_t)jo*C_SEL + 4*lane;
    f32x4 p0 = *reinterpret_cast<const f32x4*>(bb);
    f32x4 p1 = *reinterpret_cast<const f32x4*>(bb +   C_SEL);
    f32x4 p2 = *reinterpret_cast<const f32x4*>(bb + 2*C_SEL);
    f32x4 p3 = *reinterpret_cast<const f32x4*>(bb + 3*C_SEL);
    f32x4 m = p1 + 0.5f*a*((p2 - p0)
            + a*((2.f*p0 - 5.f*p1 + 4.f*p2 - p3)
            + a*(3.f*(p1 - p2) + p3 - p0)));
    *reinterpret_cast<f32x4*>(out + (size_t)t*C_SEL + 4*lane) = m;
  }
}

extern "C" void kernel_launch(void* const* d_in, const int* in_sizes, int n_in,
                              void* d_out, int out_size, void* d_ws, size_t ws_size,
                              hipStream_t stream){
  const float* firings = (const float*)d_in[0];
  const float* glow    = (const float*)d_in[1];
  const float* ghigh   = (const float*)d_in[2];
  const int*   sel     = (const int*)d_in[3];
  float* out = (float*)d_out;
  float* ws  = (float*)d_ws;

  // workspace layout (floats): ~40 MB total
  float* W1    = ws;                 // 256
  float* musum = ws + 256;           // 64 (1 used)
  float* cwh   = ws + 320;           // 1002           (ends 1322)
  float* wht   = ws + 1344;          // 1020           (ends 2364)
  float* S     = ws + 2560;          // 2000*256       (ends 514560)
  float* lowd  = ws + 514560;        // 2001*256       (ends 1026816)
  float* outd  = ws + 1026816;       // 5003*256       (ends 2307584)
  float* pbuf  = ws + 2307584;       // 5003*6*256 = 7684608 (ends 9992192)

  hipLaunchKernelGGL(kA_prep,  dim3(2),        dim3(256), 0, stream,
                     glow, ghigh, W1, musum, cwh, wht);
  hipLaunchKernelGGL(kC_conv,  dim3(NBLK),     dim3(256), 0, stream,
                     firings, sel, wht, S, pbuf);
  hipLaunchKernelGGL(kB_lowd,  dim3(501),      dim3(256), 0, stream, S, W1, lowd, musum);
  hipLaunchKernelGGL(kC_red,   dim3(1251),     dim3(256), 0, stream,
                     pbuf, cwh, lowd, musum, outd);
  hipLaunchKernelGGL(kD_interp,dim3(T_LEN/8),  dim3(256), 0, stream, outd, out);
}

// Round 10
// 376.554 us; speedup vs baseline: 1.2591x; 1.0111x over previous
//
#include <hip/hip_runtime.h>
#include <hip/hip_bf16.h>

#define T_LEN   100000   // time samples
#define C_SEL   256      // selected channels
#define C_IN    512      // input channel stride
#define KLOW    12000    // low-pass taps
#define B1      50       // low-pass decimation block
#define NB1     2000     // T_LEN / B1
#define ND1     2001     // low nodes: t = 50*jd, jd = 0..2000
#define NW1     241      // block-averaged low weights
#define ND2E    5003     // out nodes: t = 20*(jo-1), jo = 0..5002
#define WH_OFF  5500     // gauss_high truncation start (center 6000 ± 500)
#define KH      1001     // truncated high-pass taps
#define TR      200      // input rows per kC block (4 staged sub-tiles of 50)
#define NBLK    500      // T_LEN / TR
#define NAC     60       // partial nodes per block (jo in [10b-24, 10b+35])
#define NSLOT   6        // rotating partial slots (max 6 blocks per node; (b,b+6) node-disjoint)
#define WSTR    52       // padded tap-table stride (13 x f32x4)

typedef __attribute__((ext_vector_type(4))) float f32x4;

// DMA a 1KB row (64 lanes x 16B) global -> LDS (vmcnt-tracked, no VGPR cost).
__device__ __forceinline__ void stage16(const float* g, float* l){
  __builtin_amdgcn_global_load_lds((const __attribute__((address_space(1))) void*)g,
                                   (__attribute__((address_space(3))) void*)l,
                                   16, 0, 0);
}

// kA: tiny prep. block 0: W1 (block-averaged low weights), musum=0, wht
// (transposed PADDED tap table wht[p][u] = whT[20u+p-1], stride 52, zero-pad).
// block 1: cwh = prefix sums of truncated high kernel (chunked parallel scan).
__global__ __launch_bounds__(256) void kA_prep(const float* __restrict__ wlow,
                                               const float* __restrict__ whigh,
                                               float* __restrict__ W1,
                                               float* __restrict__ musum,
                                               float* __restrict__ cwh,
                                               float* __restrict__ wht){
  if (blockIdx.x == 0){
    int m1 = threadIdx.x;
    if (m1 == 0) musum[0] = 0.f;
    if (m1 < NW1){
      float s = 0.f;
      int kbase = 50*m1 - 1;
      for (int off = 0; off < 50; ++off){
        int k = kbase + off;
        if (k >= 0 && k < KLOW) s += wlow[k];
      }
      W1[m1] = s * (1.0f/50.0f);
    }
    for (int k = threadIdx.x; k < 20*WSTR; k += 256){
      int pp = k / WSTR, u = k - WSTR*pp;
      int j = 20*u + pp - 1;
      wht[k] = (u < 51 && j >= 0 && j < KH) ? whigh[WH_OFF + j] : 0.f;
    }
  } else {
    __shared__ float part[256];
    __shared__ float pre[257];
    int tg = threadIdx.x;
    float s = 0.f;
    #pragma unroll
    for (int r = 0; r < 4; ++r){ int j = 4*tg + r; if (j < KH) s += whigh[WH_OFF + j]; }
    part[tg] = s;
    __syncthreads();
    if (tg == 0){
      float run = 0.f; pre[0] = 0.f;
      for (int k = 0; k < 256; ++k){ run += part[k]; pre[k+1] = run; }
      cwh[0] = 0.f;
    }
    __syncthreads();
    float base = pre[tg], r0 = 0.f;
    #pragma unroll
    for (int r = 0; r < 4; ++r){
      int j = 4*tg + r;
      if (j < KH){ r0 += whigh[WH_OFF + j]; cwh[j+1] = base + r0; }
    }
  }
}

// One pp of a sub-tile: taps from GLOBAL (wave-uniform addr -> L1/L2 broadcast,
// VMEM/SMEM pipe) -- the R9 version read 260 broadcast ds_read_b128 per wave
// per sub-tile, oversubscribing the per-CU LDS pipe ~2.7x at 8 resident waves
// (the measured ~80us vs 17us FMA floor). Two tap chunks (6+7 f32x4) keep peak
// tap registers at 28 so total VGPR ~110 -> 16 waves/CU cap, 3 blocks resident.
// Per-acc-slot accumulation order is IDENTICAL to R9 (bit-identical results).
template<bool H0, bool H1, bool H2>
__device__ __forceinline__ void pp_fma(const float* __restrict__ wg, int pp,
                                       float v0, float v1, float v2, float* acc){
  const float* wp = wg + pp*WSTR;
  f32x4 tpc[7];
  #pragma unroll
  for (int c = 0; c < 6; ++c) tpc[c] = *reinterpret_cast<const f32x4*>(wp + 4*c);
  #pragma unroll
  for (int u = 0; u < 24; ++u){
    float tp = tpc[u>>2][u&3];
    if (H0) acc[50-u] += tp*v0;
    if (H1) acc[51-u] += tp*v1;
    if (H2) acc[52-u] += tp*v2;
  }
  #pragma unroll
  for (int c = 0; c < 7; ++c) tpc[c] = *reinterpret_cast<const f32x4*>(wp + 24 + 4*c);
  #pragma unroll
  for (int u = 24; u < 51; ++u){
    float tp = tpc[(u-24)>>2][(u-24)&3];
    if (H0) acc[50-u] += tp*v0;
    if (H1) acc[51-u] += tp*v1;
    if (H2) acc[52-u] += tp*v2;
  }
}

// 50-row sub-tile: rows t = 50b'+i, t = 20m+p, m = mbase(b')+mm, PAR = b'&1.
// Node jo = m-u+26 gets tap wht[p][u]; acc slot = mm + 50 - u (+ caller offset).
template<int PAR>
__device__ __forceinline__ void tile_conv(const float (*tile)[C_SEL],
                                          const float* __restrict__ wg,
                                          int tid, float* acc, float& ssum){
  // half 1: pp in [0,10): valid mm = PAR==0 ? {0,1,2} : {1,2}
  #pragma unroll 1
  for (int pp = 0; pp < 10; ++pp){
    if (PAR == 0){
      float v0 = tile[pp][tid], v1 = tile[20+pp][tid], v2 = tile[40+pp][tid];
      ssum += v0 + v1 + v2;
      pp_fma<true,true,true>(wg, pp, v0, v1, v2, acc);
    } else {
      float v1 = tile[10+pp][tid], v2 = tile[30+pp][tid];
      ssum += v1 + v2;
      pp_fma<false,true,true>(wg, pp, 0.f, v1, v2, acc);
    }
  }
  // half 2: pp in [10,20): valid mm = PAR==0 ? {0,1} : {0,1,2}
  #pragma unroll 1
  for (int pp = 10; pp < 20; ++pp){
    if (PAR == 0){
      float v0 = tile[pp][tid], v1 = tile[20+pp][tid];
      ssum += v0 + v1;
      pp_fma<true,true,false>(wg, pp, v0, v1, 0.f, acc);
    } else {
      float v0 = tile[pp-10][tid], v1 = tile[pp+10][tid], v2 = tile[pp+30][tid];
      ssum += v0 + v1 + v2;
      pp_fma<true,true,true>(wg, pp, v0, v1, v2, acc);
    }
  }
}

// kC: INPUT-STATIONARY conv, TR=200. Block b stages 4 sequential 50-row
// sub-tiles (same 50KB LDS buffer -- now the ONLY LDS user: 50.2KB -> 3
// blocks/CU resident, 12 waves), accumulating acc[60] in registers; one pbuf
// store at the end. Sub-tile q == old block b' = 4b+q: PAR = q&1,
// acc offset = 5*(q>>1) + 2*(q&1) = {0,2,5,7}. Emits S[4b+q] for kB free.
__global__ __launch_bounds__(256) void kC_conv(const float* __restrict__ x,
                                               const int* __restrict__ sel,
                                               const float* __restrict__ wht,
                                               float* __restrict__ S,
                                               float* __restrict__ pbuf){
  __shared__ float tile[50][C_SEL];       // 50 KB (reused by the 4 sub-tiles)
  __shared__ int okf;
  int tid = threadIdx.x;
  int b   = blockIdx.x;
  int lane = tid & 63, wid = tid >> 6;
  if (tid == 0) okf = 1;
  __syncthreads();
  if (sel[tid] != tid) okf = 0;           // benign race: all writers store 0
  __syncthreads();
  float acc[NAC];
  #pragma unroll
  for (int a = 0; a < NAC; ++a) acc[a] = 0.f;
  int ok = okf;
  int sc = sel[tid];
  #pragma unroll
  for (int q = 0; q < 4; ++q){
    const float* xrow0 = x + (size_t)(4*b + q)*(50*C_IN);
    if (ok){
      for (int i = wid; i < 50; i += 4)
        stage16(xrow0 + (size_t)i*C_IN + 4*lane, &tile[i][0]);
      asm volatile("s_waitcnt vmcnt(0)" ::: "memory");
      __syncthreads();                    // DMA visible to all waves
    } else {
      for (int i = 0; i < 50; ++i) tile[i][tid] = xrow0[(size_t)i*C_IN + sc];
      __syncthreads();
    }
    float ssum = 0.f;
    const int off = 5*(q>>1) + 2*(q&1);   // compile-time after unroll
    if (q & 1) tile_conv<1>(tile, wht, tid, acc + off, ssum);
    else       tile_conv<0>(tile, wht, tid, acc + off, ssum);
    S[(4*b + q)*C_SEL + tid] = ssum;      // 50-row block sum, free by-product
    __syncthreads();                      // all reads done before restage
  }
  // one store pass: pbuf[jo][b%6][c]; (b, b+6) write disjoint jo-ranges.
  float* pb = pbuf + (size_t)(b % NSLOT)*C_SEL + tid;
  int jo0 = 10*b - 24;
  #pragma unroll
  for (int a = 0; a < NAC; ++a){
    int jo = jo0 + a;
    if (jo >= 0 && jo < ND2E) pb[(size_t)jo*(NSLOT*C_SEL)] = acc[a];
  }
}

// kB: decimated low-pass (reads S produced by kC): lowd[jd][c] = sum W1[m1]*S[jd+m1-120][c];
// fused trapezoid-weighted musum. unroll 4 batches independent L2 loads.
__global__ __launch_bounds__(256) void kB_lowd(const float* __restrict__ S,
                                               const float* __restrict__ W1,
                                               float* __restrict__ lowd,
                                               float* __restrict__ musum){
  __shared__ float w1s[NW1];
  int tid = threadIdx.x;
  if (tid < NW1) w1s[tid] = W1[tid];
  __syncthreads();
  int jd   = blockIdx.x*4 + (tid >> 6);
  int lane = tid & 63;
  if (jd >= ND1) return;
  int lo = 120 - jd;  if (lo < 0)   lo = 0;
  int hi = 2119 - jd; if (hi > 240) hi = 240;
  f32x4 acc = {0.f, 0.f, 0.f, 0.f};
  #pragma unroll 4
  for (int m1 = lo; m1 <= hi; ++m1){
    int jb = jd + m1 - 120;
    acc += w1s[m1] * *reinterpret_cast<const f32x4*>(S + (size_t)jb*C_SEL + 4*lane);
  }
  *reinterpret_cast<f32x4*>(lowd + (size_t)jd*C_SEL + 4*lane) = acc;
  float t = acc.x + acc.y + acc.z + acc.w;
  for (int off = 32; off > 0; off >>= 1) t += __shfl_down(t, off);
  if (lane == 0){
    float ew = (jd == 0) ? 25.5f : ((jd == ND1-1) ? 24.5f : 50.f);
    atomicAdd(musum, ew*t);
  }
}

// kC_red: sum the valid block partials per node (full 6-slot unroll, loads
// issue back-to-back over 6 consecutive KB) and apply the mean/low correction.
// Invalid slots (edges: garbage/poison) masked with SELECT (NaN-safe).
__global__ __launch_bounds__(256) void kC_red(const float* __restrict__ pbuf,
                                              const float* __restrict__ cwh,
                                              const float* __restrict__ lowd,
                                              const float* __restrict__ musum,
                                              float* __restrict__ outd){
  int tid = threadIdx.x;
  int jo  = blockIdx.x*4 + (tid >> 6);
  int j   = tid & 63;
  if (jo >= ND2E) return;
  int tlo = 20*jo - 519; if (tlo < 0) tlo = 0;
  int thi = 20*jo + 481; if (thi > T_LEN-1) thi = T_LEN-1;
  int blo = tlo/TR, bhi = thi/TR;
  int cnt = bhi - blo + 1;
  int sb  = blo % NSLOT;                 // slot of first valid block
  const float* base = pbuf + (size_t)jo*(NSLOT*C_SEL) + 4*j;
  f32x4 a = {0.f, 0.f, 0.f, 0.f};
  #pragma unroll
  for (int k = 0; k < NSLOT; ++k){       // k = slot index (sequential addresses)
    f32x4 v = *reinterpret_cast<const f32x4*>(base + (size_t)k*C_SEL);
    int d = k - sb; if (d < 0) d += NSLOT;
    bool ok = (d < cnt);                 // slot holds a valid b in [blo,bhi]
    a.x += ok ? v.x : 0.f;
    a.y += ok ? v.y : 0.f;
    a.z += ok ? v.z : 0.f;
    a.w += ok ? v.w : 0.f;
  }
  float mu = musum[0] * (1.0f/((float)T_LEN*(float)C_SEL));
  int tn = 20*(jo - 1);
  int jmin = 499 - tn;             if (jmin < 0) jmin = 0;
  int jmax = T_LEN - 1 + 499 - tn; if (jmax > 1000) jmax = 1000;
  float s = cwh[jmax + 1] - cwh[jmin];
  int tc = tn < 0 ? 0 : (tn > T_LEN-1 ? T_LEN-1 : tn);
  int jd = tc/50, rr = tc - 50*jd;
  float fr = rr*(1.f/50.f);
  f32x4 l0 = *reinterpret_cast<const f32x4*>(lowd + (size_t)jd*C_SEL + 4*j);
  f32x4 l1 = *reinterpret_cast<const f32x4*>(lowd + (size_t)(jd+1)*C_SEL + 4*j);
  f32x4 lo = l0 + (l1 - l0)*fr;
  *reinterpret_cast<f32x4*>(outd + (size_t)jo*C_SEL + 4*j) = a + (mu - lo)*s;
}

// kD: Catmull-Rom interpolation back to full rate (1KB coalesced rows).
__global__ __launch_bounds__(256) void kD_interp(const float* __restrict__ outd,
                                                 float* __restrict__ out){
  int tid  = threadIdx.x;
  int lane = tid & 63;
  int w    = tid >> 6;
  int t0   = blockIdx.x*8;
  #pragma unroll
  for (int k = 0; k < 2; ++k){
    int t = t0 + w + 4*k;
    int jo = t/20, rr = t - jo*20;
    float a = rr*(1.f/20.f);
    const float* bb = outd + (size_t)jo*C_SEL + 4*lane;
    f32x4 p0 = *reinterpret_cast<const f32x4*>(bb);
    f32x4 p1 = *reinterpret_cast<const f32x4*>(bb +   C_SEL);
    f32x4 p2 = *reinterpret_cast<const f32x4*>(bb + 2*C_SEL);
    f32x4 p3 = *reinterpret_cast<const f32x4*>(bb + 3*C_SEL);
    f32x4 m = p1 + 0.5f*a*((p2 - p0)
            + a*((2.f*p0 - 5.f*p1 + 4.f*p2 - p3)
            + a*(3.f*(p1 - p2) + p3 - p0)));
    *reinterpret_cast<f32x4*>(out + (size_t)t*C_SEL + 4*lane) = m;
  }
}

extern "C" void kernel_launch(void* const* d_in, const int* in_sizes, int n_in,
                              void* d_out, int out_size, void* d_ws, size_t ws_size,
                              hipStream_t stream){
  const float* firings = (const float*)d_in[0];
  const float* glow    = (const float*)d_in[1];
  const float* ghigh   = (const float*)d_in[2];
  const int*   sel     = (const int*)d_in[3];
  float* out = (float*)d_out;
  float* ws  = (float*)d_ws;

  // workspace layout (floats): ~40 MB total
  float* W1    = ws;                 // 256
  float* musum = ws + 256;           // 64 (1 used)
  float* cwh   = ws + 320;           // 1002           (ends 1322)
  float* wht   = ws + 1344;          // 20*52 = 1040   (ends 2384)
  float* S     = ws + 2560;          // 2000*256       (ends 514560)
  float* lowd  = ws + 514560;        // 2001*256       (ends 1026816)
  float* outd  = ws + 1026816;       // 5003*256       (ends 2307584)
  float* pbuf  = ws + 2307584;       // 5003*6*256 = 7684608 (ends 9992192)

  hipLaunchKernelGGL(kA_prep,  dim3(2),        dim3(256), 0, stream,
                     glow, ghigh, W1, musum, cwh, wht);
  hipLaunchKernelGGL(kC_conv,  dim3(NBLK),     dim3(256), 0, stream,
                     firings, sel, wht, S, pbuf);
  hipLaunchKernelGGL(kB_lowd,  dim3(501),      dim3(256), 0, stream, S, W1, lowd, musum);
  hipLaunchKernelGGL(kC_red,   dim3(1251),     dim3(256), 0, stream,
                     pbuf, cwh, lowd, musum, outd);
  hipLaunchKernelGGL(kD_interp,dim3(T_LEN/8),  dim3(256), 0, stream, outd, out);
}